// Round 1
// baseline (1930.735 us; speedup 1.0000x reference)
//
#include <hip/hip_runtime.h>
#include <stdint.h>

typedef __bf16 bf16;
typedef bf16 bf16x8 __attribute__((ext_vector_type(8)));
typedef bf16 bf16x4 __attribute__((ext_vector_type(4)));
typedef float f32x4 __attribute__((ext_vector_type(4)));
typedef uint32_t u32;

#define B_TOT 16384
#define SWG 8          // samples per workgroup
#define NWGS (B_TOT / SWG)

__device__ __forceinline__ f32x4 mfma16(bf16x8 a, bf16x8 b, f32x4 c) {
  return __builtin_amdgcn_mfma_f32_16x16x32_bf16(a, b, c, 0, 0, 0);
}

__device__ __forceinline__ bf16x8 zero_bf8() {
  bf16x8 v;
#pragma unroll
  for (int j = 0; j < 8; j++) v[j] = (bf16)0.f;
  return v;
}

// Stage a logical [128 rows x 256 bytes] weight tile (row stride `rowstride` in
// global) into a 32KB LDS buffer, XOR-swizzling the GLOBAL source address so the
// linear LDS image is the swizzled layout (global_load_lds dest must be linear).
__device__ __forceinline__ void stage_issue(const uint8_t* __restrict__ src, int rowstride,
                                            uint8_t* dst, int tid) {
#pragma unroll
  for (int rr = 0; rr < 8; rr++) {
    u32 o = (u32)(rr * 256 + tid) * 16u;       // dest byte offset (lane-contiguous)
    u32 row = o >> 8;
    u32 cb = o & 0xF0u;
    const uint8_t* s = src + (size_t)row * (size_t)rowstride + (size_t)(cb ^ ((row & 7u) << 4));
    __builtin_amdgcn_global_load_lds((const __attribute__((address_space(1))) u32*)s,
                                     (__attribute__((address_space(3))) u32*)(dst + o),
                                     16, 0, 0);
  }
}

// acc[2][8] += A(32x128 from Ab, swizzled rows) @ W(128x128 from Wb, stored as
// W^T rows = out-cols, swizzled). Same slot->k map on both operands.
__device__ __forceinline__ void gemm_128(const uint8_t* Ab, const uint8_t* Wb,
                                         f32x4 acc[2][8], int g, int c) {
  const u32 sw = (u32)(c & 7) << 4;
  bf16x8 a[2][4];
#pragma unroll
  for (int mt = 0; mt < 2; mt++)
#pragma unroll
    for (int ks = 0; ks < 4; ks++)
      a[mt][ks] = *(const bf16x8*)(Ab + (u32)((mt * 16 + c) * 256) + (((u32)(ks * 64 + g * 16)) ^ sw));
#pragma unroll
  for (int ks = 0; ks < 4; ks++)
#pragma unroll
    for (int nt = 0; nt < 8; nt++) {
      bf16x8 b = *(const bf16x8*)(Wb + (u32)((nt * 16 + c) * 256) + (((u32)(ks * 64 + g * 16)) ^ sw));
      acc[0][nt] = mfma16(a[0][ks], b, acc[0][nt]);
      acc[1][nt] = mfma16(a[1][ks], b, acc[1][nt]);
    }
}

// store one bf16 into a swizzled row-major [rows][128] staging region
__device__ __forceinline__ void st_row(uint8_t* base, int row, int col, bf16 v) {
  *(bf16*)(base + (u32)(row * 256) + (u32)((2 * col) ^ ((row & 7) << 4))) = v;
}

__device__ __forceinline__ void epi_stage(const f32x4 acc[2][8], const float* __restrict__ bias,
                                          uint8_t* dst, int g, int c) {
#pragma unroll
  for (int nt = 0; nt < 8; nt++) {
    float bb = bias[nt * 16 + c];
#pragma unroll
    for (int mt = 0; mt < 2; mt++)
#pragma unroll
      for (int r = 0; r < 4; r++)
        st_row(dst, mt * 16 + 4 * g + r, nt * 16 + c, (bf16)(acc[mt][nt][r] + bb));
  }
}

// LayerNorm of x (frag layout) -> bf16 staged rows (swizzled) in dst
__device__ __forceinline__ void ln_stage(const f32x4 x[2][8], const float* __restrict__ gam,
                                         const float* __restrict__ bet,
                                         uint8_t* dst, int g, int c) {
  float gg[8], bb[8];
#pragma unroll
  for (int nt = 0; nt < 8; nt++) { gg[nt] = gam[nt * 16 + c]; bb[nt] = bet[nt * 16 + c]; }
#pragma unroll
  for (int mt = 0; mt < 2; mt++) {
    f32x4 s = {0.f, 0.f, 0.f, 0.f}, s2 = {0.f, 0.f, 0.f, 0.f};
#pragma unroll
    for (int nt = 0; nt < 8; nt++) { s += x[mt][nt]; s2 += x[mt][nt] * x[mt][nt]; }
#pragma unroll
    for (int r = 0; r < 4; r++) {
      float a = s[r], b = s2[r];
#pragma unroll
      for (int off = 1; off < 16; off <<= 1) { a += __shfl_xor(a, off); b += __shfl_xor(b, off); }
      float mean = a * (1.f / 128.f);
      float var = b * (1.f / 128.f) - mean * mean;
      float rstd = rsqrtf(var + 1e-5f);
#pragma unroll
      for (int nt = 0; nt < 8; nt++) {
        float h = (x[mt][nt][r] - mean) * rstd * gg[nt] + bb[nt];
        st_row(dst, mt * 16 + 4 * g + r, nt * 16 + c, (bf16)h);
      }
    }
  }
}

__global__ void __launch_bounds__(256, 1)
bot_main(const int* __restrict__ adj,
         const float* __restrict__ embB, const float* __restrict__ posE,
         const float* __restrict__ pbq, const float* __restrict__ pbk,
         const float* __restrict__ pbv, const float* __restrict__ pbo,
         const float* __restrict__ l1g, const float* __restrict__ l1b,
         const float* __restrict__ l2g, const float* __restrict__ l2b,
         const float* __restrict__ pb1, const float* __restrict__ pb2,
         const bf16* __restrict__ feats, const bf16* __restrict__ embWT,
         const bf16* __restrict__ wqT, const bf16* __restrict__ wkT,
         const bf16* __restrict__ wvT, const bf16* __restrict__ woT,
         const bf16* __restrict__ w1T, const bf16* __restrict__ w2T,
         float* __restrict__ out) {
  __shared__ uint8_t smem[163840];
  uint8_t* Hb  = smem;            // 32K: h, then vt (per-sample transposed V)
  uint8_t* Qb  = smem + 32768;    // 32K: Q, then attn-O, then FFN-U
  uint8_t* Kb  = smem + 65536;    // 32K: K, then h2
  uint8_t* W0  = smem + 98304;    // 32K: stage buf A (Wq, Wv, W1 chunks); P-scratch in attn
  uint8_t* W1b = smem + 131072;   // 32K: stage buf B (Wk, Wo, W2 chunks)

  const int tid = threadIdx.x;
  const int w = tid >> 6, lane = tid & 63, g = lane >> 4, c = lane & 15;
  const int S0 = blockIdx.x * SWG;
  const u32 sw = (u32)(c & 7) << 4;

  uint8_t* hreg = Hb + w * 8192;   // wave-private 32 rows
  uint8_t* qreg = Qb + w * 8192;
  uint8_t* kreg = Kb + w * 8192;
  uint8_t* pb0  = W0 + w * 1536;   // per-wave P scratch (2 samples x 768B), valid during attn

  // attention mask (constant across layers/heads/samples) -> 4 VGPRs
  float maskr[4];
#pragma unroll
  for (int r = 0; r < 4; r++) {
    int n = 4 * g + r, m = c;
    int a = adj[n * 16 + m];
    maskr[r] = (a != 0 || n == m) ? 0.f : -1e9f;
  }

  // ---------------- embed: x[b,n,:] = feats[b] @ W_n + embed_b[n] + pos_emb[n]
  float* x0 = (float*)smem;  // [8 samples][16 nodes][128] fp32 (overlays Hb+Qb)
#pragma unroll
  for (int ni = 0; ni < 4; ni++) {
    int n = w * 4 + ni;
    f32x4 acc[8] = {};
    bf16x8 af[2];
#pragma unroll
    for (int ks = 0; ks < 2; ks++)
      af[ks] = *(const bf16x8*)(feats + (size_t)(S0 + (c & 7)) * 64 + ks * 32 + g * 8);
#pragma unroll
    for (int ks = 0; ks < 2; ks++)
#pragma unroll
      for (int nt = 0; nt < 8; nt++) {
        bf16x8 b = *(const bf16x8*)(embWT + (size_t)n * 8192 + (nt * 16 + c) * 64 + ks * 32 + g * 8);
        acc[nt] = mfma16(af[ks], b, acc[nt]);
      }
    if (g < 2) {
#pragma unroll
      for (int nt = 0; nt < 8; nt++) {
        int d = nt * 16 + c;
        float eb = embB[n * 128 + d] + posE[n * 128 + d];
#pragma unroll
        for (int r = 0; r < 4; r++) {
          int smp = 4 * g + r;  // < 8 since g < 2
          x0[(smp * 16 + n) * 128 + d] = acc[nt][r] + eb;
        }
      }
    }
  }
  __syncthreads();

  f32x4 x[2][8];
#pragma unroll
  for (int mt = 0; mt < 2; mt++)
#pragma unroll
    for (int nt = 0; nt < 8; nt++)
#pragma unroll
      for (int r = 0; r < 4; r++)
        x[mt][nt][r] = x0[((2 * w + mt) * 16 + 4 * g + r) * 128 + nt * 16 + c];
  __syncthreads();  // x0 region free for h staging

  // ---------------- layers
#pragma unroll 1
  for (int l = 0; l < 4; l++) {
    const uint8_t* WqTl = (const uint8_t*)(wqT + (size_t)l * 16384);
    const uint8_t* WkTl = (const uint8_t*)(wkT + (size_t)l * 16384);
    const uint8_t* WvTl = (const uint8_t*)(wvT + (size_t)l * 16384);
    const uint8_t* WoTl = (const uint8_t*)(woT + (size_t)l * 16384);
    const uint8_t* W1Tl = (const uint8_t*)(w1T + (size_t)l * 65536);
    const uint8_t* W2Tl = (const uint8_t*)(w2T + (size_t)l * 65536);

    stage_issue(WqTl, 256, W0, tid);                // Wq loads hide under LN1
    ln_stage(x, l1g + l * 128, l1b + l * 128, hreg, g, c);
    __syncthreads();                                // Wq ready

    stage_issue(WkTl, 256, W1b, tid);
    {
      f32x4 acc[2][8] = {};
      gemm_128(hreg, W0, acc, g, c);
      epi_stage(acc, pbq + l * 128, qreg, g, c);    // Q -> q_lds
    }
    __syncthreads();                                // Wk ready, W0 free

    stage_issue(WvTl, 256, W0, tid);
    {
      f32x4 acc[2][8] = {};
      gemm_128(hreg, W1b, acc, g, c);
      epi_stage(acc, pbk + l * 128, kreg, g, c);    // K -> k_lds
    }
    __syncthreads();                                // Wv ready, W1b free

    stage_issue(WoTl, 256, W1b, tid);
    {
      f32x4 acc[2][8] = {};
      gemm_128(hreg, W0, acc, g, c);
      // V epilogue: store TRANSPOSED per sample: vt[d][m], overwrites h (A-frags
      // were preloaded into regs, wave-private region -> safe)
#pragma unroll
      for (int mt = 0; mt < 2; mt++)
#pragma unroll
        for (int nt = 0; nt < 8; nt++) {
          float bb = pbv[l * 128 + nt * 16 + c];
          bf16x4 pk;
#pragma unroll
          for (int r = 0; r < 4; r++) pk[r] = (bf16)(acc[mt][nt][r] + bb);
          *(bf16x4*)(hreg + mt * 4096 + (nt * 16 + c) * 32 + g * 8) = pk;
        }
    }
    __syncthreads();                                // Wo ready, W0 free (P scratch ok)

    // ---------------- attention (wave-private; both samples' pipelines interleaved)
    {
      f32x4 oacc[2][8] = {};
#pragma unroll
      for (int hh = 0; hh < 8; hh++) {
#pragma unroll
        for (int mt = 0; mt < 2; mt++) {
          const uint8_t* qs = qreg + mt * 4096;
          const uint8_t* ks_ = kreg + mt * 4096;
          const uint8_t* vs = hreg + mt * 4096;
          uint8_t* pbm = pb0 + mt * 768;
          bf16x8 aq = zero_bf8(), bkf = zero_bf8();
          if (g < 2) {
            aq  = *(const bf16x8*)(qs  + (u32)(c * 256) + (((u32)(hh * 32 + g * 16)) ^ sw));
            bkf = *(const bf16x8*)(ks_ + (u32)(c * 256) + (((u32)(hh * 32 + g * 16)) ^ sw));
          }
          f32x4 z4 = {0.f, 0.f, 0.f, 0.f};
          f32x4 sc = mfma16(aq, bkf, z4);
          float p[4], mx[4], sm[4];
#pragma unroll
          for (int r = 0; r < 4; r++) { p[r] = sc[r] * 0.25f + maskr[r]; mx[r] = p[r]; }
#pragma unroll
          for (int off = 1; off < 16; off <<= 1)
#pragma unroll
            for (int r = 0; r < 4; r++) mx[r] = fmaxf(mx[r], __shfl_xor(mx[r], off));
#pragma unroll
          for (int r = 0; r < 4; r++) { p[r] = __expf(p[r] - mx[r]); sm[r] = p[r]; }
#pragma unroll
          for (int off = 1; off < 16; off <<= 1)
#pragma unroll
            for (int r = 0; r < 4; r++) sm[r] += __shfl_xor(sm[r], off);
#pragma unroll
          for (int r = 0; r < 4; r++)
            *(bf16*)(pbm + (4 * g + r) * 48 + c * 2) = (bf16)(p[r] * __fdividef(1.f, sm[r]));
          bf16x8 ap = zero_bf8(), bvf = zero_bf8();
          if (g < 2) {
            ap  = *(const bf16x8*)(pbm + c * 48 + g * 16);
            bvf = *(const bf16x8*)(vs + (hh * 16 + c) * 32 + g * 16);
          }
          oacc[mt][hh] = mfma16(ap, bvf, oacc[mt][hh]);
        }
      }
      // O -> q_lds (Q fully consumed; wave-private)
#pragma unroll
      for (int mt = 0; mt < 2; mt++)
#pragma unroll
        for (int hh = 0; hh < 8; hh++)
#pragma unroll
          for (int r = 0; r < 4; r++)
            st_row(qreg, mt * 16 + 4 * g + r, hh * 16 + c, (bf16)oacc[mt][hh][r]);
    }
    __syncthreads();                                // attn done everywhere, W0 free

    stage_issue(W1Tl, 256, W0, tid);                // W1 chunk 0; hides under O-proj+LN2
    gemm_128(qreg, W1b, x, g, c);                   // x += O @ Wo
#pragma unroll
    for (int nt = 0; nt < 8; nt++) {
      float bb = pbo[l * 128 + nt * 16 + c];
#pragma unroll
      for (int mt = 0; mt < 2; mt++)
#pragma unroll
        for (int r = 0; r < 4; r++) x[mt][nt][r] += bb;
    }
    ln_stage(x, l2g + l * 128, l2b + l * 128, kreg, g, c);  // h2 -> k_lds
    __syncthreads();                                // W1c0 ready, W1b free

#pragma unroll 1
    for (int fc = 0; fc < 4; fc++) {
      stage_issue(W2Tl + fc * 256, 1024, W1b, tid); // W2 k-chunk; hides under U-gemm
      {
        f32x4 u[2][8] = {};
        gemm_128(kreg, W0, u, g, c);
#pragma unroll
        for (int nt = 0; nt < 8; nt++) {
          float bb = pb1[l * 512 + fc * 128 + nt * 16 + c];
#pragma unroll
          for (int mt = 0; mt < 2; mt++)
#pragma unroll
            for (int r = 0; r < 4; r++)
              st_row(qreg, mt * 16 + 4 * g + r, nt * 16 + c,
                     (bf16)fmaxf(u[mt][nt][r] + bb, 0.f));  // relu(U) -> q_lds
        }
      }
      __syncthreads();                              // W2c ready, W0 free
      if (fc < 3) stage_issue(W1Tl + (fc + 1) * 32768, 256, W0, tid);  // hides under Y-gemm
      gemm_128(qreg, W1b, x, g, c);                 // x += U @ W2c
      __syncthreads();                              // next W1c ready, W1b free
    }
#pragma unroll
    for (int nt = 0; nt < 8; nt++) {
      float bb = pb2[l * 128 + nt * 16 + c];
#pragma unroll
      for (int mt = 0; mt < 2; mt++)
#pragma unroll
        for (int r = 0; r < 4; r++) x[mt][nt][r] += bb;
    }
  }

  // ---------------- output (fp32)
#pragma unroll
  for (int mt = 0; mt < 2; mt++)
#pragma unroll
    for (int nt = 0; nt < 8; nt++)
#pragma unroll
      for (int r = 0; r < 4; r++)
        out[(size_t)(S0 + 2 * w + mt) * 2048 + (4 * g + r) * 128 + nt * 16 + c] = x[mt][nt][r];
}

// ---------------- prep kernels ----------------
__global__ void prep_feats_k(const float* __restrict__ pos, const float* __restrict__ vel,
                             bf16* __restrict__ feats) {
  int i = blockIdx.x * 256 + threadIdx.x;
  if (i >= B_TOT * 64) return;
  int b = i >> 6, k = i & 63;
  float v = (k < 32) ? pos[b * 32 + k] : vel[b * 32 + (k - 32)];
  feats[i] = (bf16)v;
}

// dst[m][cc][rr] = (bf16) src[m][rr][cc]; src is [mats][R][C] fp32
__global__ void prep_tr_k(const float* __restrict__ src, bf16* __restrict__ dst,
                          int R, int C, int total) {
  int i = blockIdx.x * 256 + threadIdx.x;
  if (i >= total) return;
  int rc = R * C;
  int m = i / rc, rem = i % rc;
  int cc = rem / R, rr = rem % R;
  dst[i] = (bf16)src[(size_t)m * rc + rr * C + cc];
}

extern "C" void kernel_launch(void* const* d_in, const int* in_sizes, int n_in,
                              void* d_out, int out_size, void* d_ws, size_t ws_size,
                              hipStream_t stream) {
  const float* jp  = (const float*)d_in[0];
  const float* jv  = (const float*)d_in[1];
  const int*   adj = (const int*)d_in[2];
  const float* eW  = (const float*)d_in[3];
  const float* eB  = (const float*)d_in[4];
  const float* pE  = (const float*)d_in[5];
  const float* Wq  = (const float*)d_in[6];  const float* bq = (const float*)d_in[7];
  const float* Wk  = (const float*)d_in[8];  const float* bk = (const float*)d_in[9];
  const float* Wv  = (const float*)d_in[10]; const float* bv = (const float*)d_in[11];
  const float* Wo  = (const float*)d_in[12]; const float* bo = (const float*)d_in[13];
  const float* g1  = (const float*)d_in[14]; const float* be1 = (const float*)d_in[15];
  const float* g2  = (const float*)d_in[16]; const float* be2 = (const float*)d_in[17];
  const float* W1  = (const float*)d_in[18]; const float* b1 = (const float*)d_in[19];
  const float* W2  = (const float*)d_in[20]; const float* b2 = (const float*)d_in[21];

  bf16* ws    = (bf16*)d_ws;
  bf16* feats = ws;                    // 1048576
  bf16* embWT = ws + 1048576;          // 131072  [16][128][64]
  bf16* wqT   = embWT + 131072;        // 65536   [4][128 out][128 in]
  bf16* wkT   = wqT + 65536;
  bf16* wvT   = wkT + 65536;
  bf16* woT   = wvT + 65536;
  bf16* w1T   = woT + 65536;           // 262144  [4][512 f][128 in]
  bf16* w2T   = w1T + 262144;          // 262144  [4][128 out][512 f]

  prep_feats_k<<<(B_TOT * 64 + 255) / 256, 256, 0, stream>>>(jp, jv, feats);
  prep_tr_k<<<512, 256, 0, stream>>>(eW, embWT, 64, 128, 131072);
  prep_tr_k<<<256, 256, 0, stream>>>(Wq, wqT, 128, 128, 65536);
  prep_tr_k<<<256, 256, 0, stream>>>(Wk, wkT, 128, 128, 65536);
  prep_tr_k<<<256, 256, 0, stream>>>(Wv, wvT, 128, 128, 65536);
  prep_tr_k<<<256, 256, 0, stream>>>(Wo, woT, 128, 128, 65536);
  prep_tr_k<<<1024, 256, 0, stream>>>(W1, w1T, 128, 512, 262144);
  prep_tr_k<<<1024, 256, 0, stream>>>(W2, w2T, 512, 128, 262144);

  bot_main<<<NWGS, 256, 0, stream>>>(adj, eB, pE, bq, bk, bv, bo,
                                     g1, be1, g2, be2, b1, b2,
                                     feats, embWT, wqT, wkT, wvT, woT, w1T, w2T,
                                     (float*)d_out);
}

// Round 4
// 1202.917 us; speedup vs baseline: 1.6050x; 1.6050x over previous
//
#include <hip/hip_runtime.h>
#include <stdint.h>

typedef __bf16 bf16;
typedef bf16 bf16x8 __attribute__((ext_vector_type(8)));
typedef bf16 bf16x4 __attribute__((ext_vector_type(4)));
typedef float f32x4 __attribute__((ext_vector_type(4)));
typedef uint32_t u32;
typedef uint8_t u8;

#define B_TOT 16384
#define SWG 8
#define NWGS (B_TOT / SWG)   // 2048

__device__ __forceinline__ f32x4 mfma32(bf16x8 a, bf16x8 b, f32x4 c) {
  return __builtin_amdgcn_mfma_f32_16x16x32_bf16(a, b, c, 0, 0, 0);
}
__device__ __forceinline__ bf16x8 zero8() {
  bf16x8 v;
#pragma unroll
  for (int j = 0; j < 8; j++) v[j] = (bf16)0.f;
  return v;
}

// ordering fence between same-wave LDS store->load (round-1-verified pattern)
__device__ __forceinline__ void lds_fence() {
  __builtin_amdgcn_sched_barrier(0);
  asm volatile("s_waitcnt lgkmcnt(0)");
  __builtin_amdgcn_sched_barrier(0);
}

// Stage one [128 rows x 128 bytes] weight K-half (16KB) into an LDS buffer.
// Swizzle applied on the GLOBAL source address (byte ^ ((row&7)<<4)); the
// linear LDS image is then the swizzled layout; reads apply the same XOR.
__device__ __forceinline__ void stage16(const u8* __restrict__ src, int rowstride, int colbase,
                                        u8* dst, int tid) {
#pragma unroll
  for (int rr = 0; rr < 2; ++rr) {
    u32 o = (u32)(rr * 512 + tid) * 16u;
    u32 row = o >> 7, cb = o & 0x7Fu;
    const u8* s = src + (size_t)row * (size_t)rowstride + (size_t)colbase
                      + (size_t)(cb ^ ((row & 7u) << 4));
    __builtin_amdgcn_global_load_lds((const __attribute__((address_space(1))) u32*)s,
                                     (__attribute__((address_space(3))) u32*)(dst + o),
                                     16, 0, 0);
  }
}

// scalar store into swizzled row-major [32 rows][128 cols] bf16 tile
__device__ __forceinline__ void st_row(u8* base, int row, int col, bf16 v) {
  *(bf16*)(base + (u32)(row * 256) + (u32)((2 * col) ^ ((row & 7) << 4))) = v;
}

// A-fragments (2 samples, full K=128) from swizzled row-major tile (verified r1)
__device__ __forceinline__ void loadA_rm(const u8* R, int g, int c, bf16x8 a[2][4]) {
  const u32 sw = (u32)(c & 7) << 4;
#pragma unroll
  for (int mt = 0; mt < 2; ++mt)
#pragma unroll
    for (int ks = 0; ks < 4; ++ks)
      a[mt][ks] = *(const bf16x8*)(R + (u32)((mt * 16 + c) * 256)
                                     + (((u32)(ks * 64 + g * 16)) ^ sw));
}

// acc[2][4] += A-half @ W-half. Wb = 16KB staged half (rows=outcols, 128B k-rows,
// swizzled). khalf selects the A-frag ks-pair. Wave covers outcols nh*64..+63.
__device__ __forceinline__ void gemm_half(const u8* Wb, int khalf, const bf16x8 a[2][4],
                                          f32x4 acc[2][4], int nh, int g, int c) {
  const u32 sw = (u32)(c & 7) << 4;
#pragma unroll
  for (int ksl = 0; ksl < 2; ++ksl) {
    int ks = khalf * 2 + ksl;
#pragma unroll
    for (int nt = 0; nt < 4; ++nt) {
      bf16x8 b = *(const bf16x8*)(Wb + (u32)((nh * 64 + nt * 16 + c) * 128)
                                     + (((u32)(ksl * 64 + g * 16)) ^ sw));
      acc[0][nt] = mfma32(a[0][ks], b, acc[0][nt]);
      acc[1][nt] = mfma32(a[1][ks], b, acc[1][nt]);
    }
  }
}

// C-fragment epilogue -> swizzled row-major tile, scalar stores (verified r1)
template <bool RELU>
__device__ __forceinline__ void epi_rm(const f32x4 acc[2][4], const float* __restrict__ bias,
                                       u8* Rdst, int nh, int g, int c) {
#pragma unroll
  for (int nt = 0; nt < 4; ++nt) {
    int col = nh * 64 + nt * 16 + c;
    float bb = bias[col];
#pragma unroll
    for (int mt = 0; mt < 2; ++mt)
#pragma unroll
      for (int r = 0; r < 4; ++r) {
        float v = acc[mt][nt][r] + bb;
        if (RELU) v = fmaxf(v, 0.f);
        st_row(Rdst, mt * 16 + 4 * g + r, col, (bf16)v);
      }
  }
}

__device__ __forceinline__ void ln_part(const f32x4 x[2][4], float sS[2][4], float sS2[2][4]) {
#pragma unroll
  for (int mt = 0; mt < 2; ++mt) {
    f32x4 a = {0.f, 0.f, 0.f, 0.f}, b = {0.f, 0.f, 0.f, 0.f};
#pragma unroll
    for (int nt = 0; nt < 4; ++nt) { a += x[mt][nt]; b += x[mt][nt] * x[mt][nt]; }
#pragma unroll
    for (int r = 0; r < 4; ++r) {
      float s = a[r], s2 = b[r];
#pragma unroll
      for (int off = 1; off < 16; off <<= 1) { s += __shfl_xor(s, off); s2 += __shfl_xor(s2, off); }
      sS[mt][r] = s; sS2[mt][r] = s2;
    }
  }
}

__global__ void __launch_bounds__(512, 2)
bot_main(const int* __restrict__ adj,
         const float* __restrict__ embB, const float* __restrict__ posE,
         const float* __restrict__ pbq, const float* __restrict__ pbk,
         const float* __restrict__ pbv, const float* __restrict__ pbo,
         const float* __restrict__ l1g, const float* __restrict__ l1b,
         const float* __restrict__ l2g, const float* __restrict__ l2b,
         const float* __restrict__ pb1, const float* __restrict__ pb2,
         const bf16* __restrict__ feats, const bf16* __restrict__ embWT,
         const bf16* __restrict__ wqT, const bf16* __restrict__ wkT,
         const bf16* __restrict__ wvT, const bf16* __restrict__ woT,
         const bf16* __restrict__ w1T, const bf16* __restrict__ w2T,
         float* __restrict__ out) {
  __shared__ u8 smem[163840];
  const int tid = threadIdx.x;
  const int w = tid >> 6, lane = tid & 63, g = lane >> 4, c = lane & 15;
  const int p = w >> 1, nh = w & 1;           // pair index, N-half
  const int S0 = blockIdx.x * SWG;
  const u32 sw = (u32)(c & 7) << 4;

  u8* pairb = smem + p * 32768;
  u8* Rh = pairb;            // h / h2: row-major [32 rows][128 cols] swizzled
  u8* Rq = pairb + 8192;     // q / P / O / U (row-major swizzled)
  u8* Rk = pairb + 16384;    // k (row-major swizzled); LN scratch at base when dead
  u8* Rv = pairb + 24576;    // vt: per-sample col-major [128 d][16 n]
  u8* WB0 = smem + 131072;   // weight K-half buffers (16KB each)
  u8* WB1 = smem + 147456;
  float* scr = (float*)Rk;

  float maskr[4];
#pragma unroll
  for (int r = 0; r < 4; ++r) {
    int n = 4 * g + r;
    maskr[r] = (adj[n * 16 + c] != 0 || n == c) ? 0.f : -1e9f;
  }

  // ---------------- embed (WG-cooperative, transient x0 in LDS) ----------------
  {
    float* x0 = (float*)smem;  // [8 samples][2048]
    f32x4 ea[16] = {};
    bf16x8 af[2];
#pragma unroll
    for (int ks = 0; ks < 2; ++ks)
      af[ks] = *(const bf16x8*)(feats + (size_t)(S0 + (c & 7)) * 64 + ks * 32 + g * 8);
#pragma unroll
    for (int nt = 0; nt < 16; ++nt) {
#pragma unroll
      for (int ks = 0; ks < 2; ++ks) {
        bf16x8 bw = *(const bf16x8*)(embWT + (size_t)(w * 256 + nt * 16 + c) * 64 + ks * 32 + g * 8);
        ea[nt] = mfma32(af[ks], bw, ea[nt]);
      }
    }
    if (g < 2) {
#pragma unroll
      for (int nt = 0; nt < 16; ++nt)
#pragma unroll
        for (int r = 0; r < 4; ++r)
          x0[(4 * g + r) * 2048 + w * 256 + nt * 16 + c] = ea[nt][r];
    }
  }
  __syncthreads();

  f32x4 x[2][4];
  {
    const float* x0 = (const float*)smem;
#pragma unroll
    for (int nt = 0; nt < 4; ++nt)
#pragma unroll
      for (int r = 0; r < 4; ++r) {
        int n = 4 * g + r, d = nh * 64 + nt * 16 + c;
        float eb = embB[n * 128 + d] + posE[n * 128 + d];
#pragma unroll
        for (int mt = 0; mt < 2; ++mt)
          x[mt][nt][r] = x0[(2 * p + mt) * 2048 + n * 128 + d] + eb;
      }
  }
  __syncthreads();

  bf16x8 Ah[2][4], Ah2[2][4], Au[2][4];

  // ---------------- layers: lag-1 staged slot pipeline ----------------
#pragma unroll 1
  for (int l = 0; l < 4; ++l) {
    const u8* Wq_l = (const u8*)(wqT + (size_t)l * 16384);
    const u8* Wk_l = (const u8*)(wkT + (size_t)l * 16384);
    const u8* Wv_l = (const u8*)(wvT + (size_t)l * 16384);
    const u8* Wo_l = (const u8*)(woT + (size_t)l * 16384);
    const u8* W1_l = (const u8*)(w1T + (size_t)l * 65536);
    const u8* W2_l = (const u8*)(w2T + (size_t)l * 65536);

    float sS[2][4], sS2[2][4], mean[2][4], rstd[2][4];

    // slot1: LN1 partials (this wave's 64 dims)
    ln_part(x, sS, sS2);
    if (c == 0) {
#pragma unroll
      for (int mt = 0; mt < 2; ++mt)
#pragma unroll
        for (int r = 0; r < 4; ++r) {
          int row = mt * 16 + 4 * g + r;
          scr[(row * 2 + nh) * 2 + 0] = sS[mt][r];
          scr[(row * 2 + nh) * 2 + 1] = sS2[mt][r];
        }
    }
    __syncthreads();

    // slot2: stage Q-h0; LN1 combine + h store (row-major swizzled, scalar)
    stage16(Wq_l, 256, 0, WB0, tid);
#pragma unroll
    for (int mt = 0; mt < 2; ++mt)
#pragma unroll
      for (int r = 0; r < 4; ++r) {
        int row = mt * 16 + 4 * g + r;
        float s = sS[mt][r] + scr[(row * 2 + (1 - nh)) * 2 + 0];
        float s2 = sS2[mt][r] + scr[(row * 2 + (1 - nh)) * 2 + 1];
        float mu = s * (1.f / 128.f);
        float va = s2 * (1.f / 128.f) - mu * mu;
        mean[mt][r] = mu; rstd[mt][r] = rsqrtf(va + 1e-5f);
      }
#pragma unroll
    for (int nt = 0; nt < 4; ++nt) {
      int col = nh * 64 + nt * 16 + c;
      float gg = l1g[l * 128 + col], bb = l1b[l * 128 + col];
#pragma unroll
      for (int mt = 0; mt < 2; ++mt)
#pragma unroll
        for (int r = 0; r < 4; ++r)
          st_row(Rh, mt * 16 + 4 * g + r, col,
                 (bf16)((x[mt][nt][r] - mean[mt][r]) * rstd[mt][r] * gg + bb));
    }
    __syncthreads();

    f32x4 acc[2][4];
    // slot3: stage Q-h1; loadA(h); Q-gemm h0
    stage16(Wq_l, 256, 128, WB1, tid);
    loadA_rm(Rh, g, c, Ah);
#pragma unroll
    for (int mt = 0; mt < 2; ++mt)
#pragma unroll
      for (int nt = 0; nt < 4; ++nt) acc[mt][nt] = (f32x4){0.f, 0.f, 0.f, 0.f};
    gemm_half(WB0, 0, Ah, acc, nh, g, c);
    __syncthreads();
    // slot4: stage K-h0; Q-gemm h1 + q epi
    stage16(Wk_l, 256, 0, WB0, tid);
    gemm_half(WB1, 1, Ah, acc, nh, g, c);
    epi_rm<false>(acc, pbq + l * 128, Rq, nh, g, c);
    __syncthreads();
    // slot5: stage K-h1; K-gemm h0
    stage16(Wk_l, 256, 128, WB1, tid);
#pragma unroll
    for (int mt = 0; mt < 2; ++mt)
#pragma unroll
      for (int nt = 0; nt < 4; ++nt) acc[mt][nt] = (f32x4){0.f, 0.f, 0.f, 0.f};
    gemm_half(WB0, 0, Ah, acc, nh, g, c);
    __syncthreads();
    // slot6: stage V-h0; K-gemm h1 + k epi
    stage16(Wv_l, 256, 0, WB0, tid);
    gemm_half(WB1, 1, Ah, acc, nh, g, c);
    epi_rm<false>(acc, pbk + l * 128, Rk, nh, g, c);
    __syncthreads();
    // slot7: stage V-h1; V-gemm h0
    stage16(Wv_l, 256, 128, WB1, tid);
#pragma unroll
    for (int mt = 0; mt < 2; ++mt)
#pragma unroll
      for (int nt = 0; nt < 4; ++nt) acc[mt][nt] = (f32x4){0.f, 0.f, 0.f, 0.f};
    gemm_half(WB0, 0, Ah, acc, nh, g, c);
    __syncthreads();
    // slot8: (no stage); V-gemm h1 + v epi TRANSPOSED (col-major vt, vector b64)
    gemm_half(WB1, 1, Ah, acc, nh, g, c);
#pragma unroll
    for (int nt = 0; nt < 4; ++nt) {
      int col = nh * 64 + nt * 16 + c;
      float bb = pbv[l * 128 + col];
#pragma unroll
      for (int mt = 0; mt < 2; ++mt) {
        bf16x4 pk;
#pragma unroll
        for (int r = 0; r < 4; ++r) pk[r] = (bf16)(acc[mt][nt][r] + bb);
        *(bf16x4*)(Rv + mt * 4096 + col * 32 + g * 8) = pk;
      }
    }
    __syncthreads();

    // slot9: stage O-h0; ATTENTION (this wave's 4 heads, both samples) — r1 paths
    stage16(Wo_l, 256, 0, WB0, tid);
    {
      const f32x4 zz = {0.f, 0.f, 0.f, 0.f};
#pragma unroll 1
      for (int hh = 0; hh < 4; ++hh) {
        const int gh = nh * 4 + hh;
        bf16x8 qf[2], kf[2];
#pragma unroll
        for (int mt = 0; mt < 2; ++mt) {
          if (g < 2) {
            qf[mt] = *(const bf16x8*)(Rq + (u32)((mt * 16 + c) * 256)
                                         + (((u32)(gh * 32 + g * 16)) ^ sw));
            kf[mt] = *(const bf16x8*)(Rk + (u32)((mt * 16 + c) * 256)
                                         + (((u32)(gh * 32 + g * 16)) ^ sw));
          } else { qf[mt] = zero8(); kf[mt] = zero8(); }
        }
        f32x4 sc[2];
        sc[0] = mfma32(qf[0], kf[0], zz);
        sc[1] = mfma32(qf[1], kf[1], zz);
        float pr[2][4], mx[2][4], sm[2][4];
#pragma unroll
        for (int mt = 0; mt < 2; ++mt)
#pragma unroll
          for (int r = 0; r < 4; ++r) { pr[mt][r] = sc[mt][r] * 0.25f + maskr[r]; mx[mt][r] = pr[mt][r]; }
#pragma unroll
        for (int off = 1; off < 16; off <<= 1)
#pragma unroll
          for (int mt = 0; mt < 2; ++mt)
#pragma unroll
            for (int r = 0; r < 4; ++r) mx[mt][r] = fmaxf(mx[mt][r], __shfl_xor(mx[mt][r], off));
#pragma unroll
        for (int mt = 0; mt < 2; ++mt)
#pragma unroll
          for (int r = 0; r < 4; ++r) { pr[mt][r] = __expf(pr[mt][r] - mx[mt][r]); sm[mt][r] = pr[mt][r]; }
#pragma unroll
        for (int off = 1; off < 16; off <<= 1)
#pragma unroll
          for (int mt = 0; mt < 2; ++mt)
#pragma unroll
            for (int r = 0; r < 4; ++r) sm[mt][r] += __shfl_xor(sm[mt][r], off);
        // P over dead Q head-block (scalar st_row, same-wave)
#pragma unroll
        for (int mt = 0; mt < 2; ++mt)
#pragma unroll
          for (int r = 0; r < 4; ++r)
            st_row(Rq, mt * 16 + 4 * g + r, gh * 16 + c,
                   (bf16)(pr[mt][r] * __fdividef(1.f, sm[mt][r])));
        lds_fence();
        // P as A-frag (linear swizzled read) + V as B-frag (linear read)
        bf16x8 pa[2], vf[2];
#pragma unroll
        for (int mt = 0; mt < 2; ++mt) {
          if (g < 2) {
            pa[mt] = *(const bf16x8*)(Rq + (u32)((mt * 16 + c) * 256)
                                         + (((u32)(gh * 32 + g * 16)) ^ sw));
            vf[mt] = *(const bf16x8*)(Rv + mt * 4096 + gh * 512 + c * 32 + g * 16);
          } else { pa[mt] = zero8(); vf[mt] = zero8(); }
        }
        f32x4 oo[2];
        oo[0] = mfma32(pa[0], vf[0], zz);
        oo[1] = mfma32(pa[1], vf[1], zz);
        // O over P (same block, same-wave sequential)
#pragma unroll
        for (int mt = 0; mt < 2; ++mt)
#pragma unroll
          for (int r = 0; r < 4; ++r)
            st_row(Rq, mt * 16 + 4 * g + r, gh * 16 + c, (bf16)oo[mt][r]);
      }
    }
    __syncthreads();

    // slot10: stage O-h1; loadA(O); O-proj h0 into x
    stage16(Wo_l, 256, 128, WB1, tid);
    loadA_rm(Rq, g, c, Ah);
    gemm_half(WB0, 0, Ah, x, nh, g, c);
    __syncthreads();
    // slot11: (no stage); O-proj h1 + bo + LN2 partials
    gemm_half(WB1, 1, Ah, x, nh, g, c);
#pragma unroll
    for (int nt = 0; nt < 4; ++nt) {
      float bb = pbo[l * 128 + nh * 64 + nt * 16 + c];
#pragma unroll
      for (int mt = 0; mt < 2; ++mt)
#pragma unroll
        for (int r = 0; r < 4; ++r) x[mt][nt][r] += bb;
    }
    ln_part(x, sS, sS2);
    if (c == 0) {
#pragma unroll
      for (int mt = 0; mt < 2; ++mt)
#pragma unroll
        for (int r = 0; r < 4; ++r) {
          int row = mt * 16 + 4 * g + r;
          scr[(row * 2 + nh) * 2 + 0] = sS[mt][r];
          scr[(row * 2 + nh) * 2 + 1] = sS2[mt][r];
        }
    }
    __syncthreads();

    // slot12: stage W1c0-h0; LN2 combine + h2 store (into Rh, h dead)
    stage16(W1_l, 256, 0, WB0, tid);
#pragma unroll
    for (int mt = 0; mt < 2; ++mt)
#pragma unroll
      for (int r = 0; r < 4; ++r) {
        int row = mt * 16 + 4 * g + r;
        float s = sS[mt][r] + scr[(row * 2 + (1 - nh)) * 2 + 0];
        float s2 = sS2[mt][r] + scr[(row * 2 + (1 - nh)) * 2 + 1];
        float mu = s * (1.f / 128.f);
        float va = s2 * (1.f / 128.f) - mu * mu;
        mean[mt][r] = mu; rstd[mt][r] = rsqrtf(va + 1e-5f);
      }
#pragma unroll
    for (int nt = 0; nt < 4; ++nt) {
      int col = nh * 64 + nt * 16 + c;
      float gg = l2g[l * 128 + col], bb = l2b[l * 128 + col];
#pragma unroll
      for (int mt = 0; mt < 2; ++mt)
#pragma unroll
        for (int r = 0; r < 4; ++r)
          st_row(Rh, mt * 16 + 4 * g + r, col,
                 (bf16)((x[mt][nt][r] - mean[mt][r]) * rstd[mt][r] * gg + bb));
    }
    __syncthreads();

    // ---------------- FFN: per chunk 4 slots ----------------
#pragma unroll 1
    for (int fc = 0; fc < 4; ++fc) {
      f32x4 uacc[2][4];
#pragma unroll
      for (int mt = 0; mt < 2; ++mt)
#pragma unroll
        for (int nt = 0; nt < 4; ++nt) uacc[mt][nt] = (f32x4){0.f, 0.f, 0.f, 0.f};
      // sU0: stage W1c_fc-h1; (fc==0: loadA h2); U-gemm h0
      stage16(W1_l + fc * 32768, 256, 128, WB1, tid);
      if (fc == 0) loadA_rm(Rh, g, c, Ah2);
      gemm_half(WB0, 0, Ah2, uacc, nh, g, c);
      __syncthreads();
      // sU1: stage W2c_fc-h0; U-gemm h1 + relu epi -> Rq
      stage16(W2_l, 1024, fc * 256, WB0, tid);
      gemm_half(WB1, 1, Ah2, uacc, nh, g, c);
      epi_rm<true>(uacc, pb1 + l * 512 + fc * 128, Rq, nh, g, c);
      __syncthreads();
      // sY0: stage W2c_fc-h1; loadA(U); Y-gemm h0 into x
      stage16(W2_l, 1024, fc * 256 + 128, WB1, tid);
      loadA_rm(Rq, g, c, Au);
      gemm_half(WB0, 0, Au, x, nh, g, c);
      __syncthreads();
      // sY1: stage W1c_{fc+1}-h0; Y-gemm h1 into x
      if (fc < 3) stage16(W1_l + (fc + 1) * 32768, 256, 0, WB0, tid);
      gemm_half(WB1, 1, Au, x, nh, g, c);
      __syncthreads();
    }
    // b2
#pragma unroll
    for (int nt = 0; nt < 4; ++nt) {
      float bb = pb2[l * 128 + nh * 64 + nt * 16 + c];
#pragma unroll
      for (int mt = 0; mt < 2; ++mt)
#pragma unroll
        for (int r = 0; r < 4; ++r) x[mt][nt][r] += bb;
    }
  }

  // ---------------- output: LDS bounce -> fully coalesced fp32 stores ----------------
#pragma unroll
  for (int nt = 0; nt < 4; ++nt) {
    int col = nh * 64 + nt * 16 + c;
#pragma unroll
    for (int mt = 0; mt < 2; ++mt)
      *(f32x4*)(pairb + mt * 8192 + col * 64 + g * 16) = x[mt][nt];
  }
  __syncthreads();
  {
    const int smp = S0 + 2 * p + nh;
    const u8* src = pairb + nh * 8192;
#pragma unroll
    for (int it = 0; it < 8; ++it) {
      int n = it * 2 + (lane >> 5);
      int slot = lane & 31;
      f32x4 v;
#pragma unroll
      for (int e = 0; e < 4; ++e)
        v[e] = *(const float*)(src + (u32)((slot * 4 + e) * 64 + n * 4));
      *(f32x4*)(out + (size_t)smp * 2048 + n * 128 + slot * 4) = v;
    }
  }
}

// ---------------- prep kernels ----------------
__global__ void prep_feats_k(const float* __restrict__ pos, const float* __restrict__ vel,
                             bf16* __restrict__ feats) {
  int i = blockIdx.x * 256 + threadIdx.x;
  if (i >= B_TOT * 64) return;
  int b = i >> 6, k = i & 63;
  float v = (k < 32) ? pos[b * 32 + k] : vel[b * 32 + (k - 32)];
  feats[i] = (bf16)v;
}

// dst[m][cc][rr] = (bf16) src[m][rr][cc]; src is [mats][R][C] fp32
__global__ void prep_tr_k(const float* __restrict__ src, bf16* __restrict__ dst,
                          int R, int C, int total) {
  int i = blockIdx.x * 256 + threadIdx.x;
  if (i >= total) return;
  int rc = R * C;
  int m = i / rc, rem = i % rc;
  int cc = rem / R, rr = rem % R;
  dst[i] = (bf16)src[(size_t)m * rc + rr * C + cc];
}

extern "C" void kernel_launch(void* const* d_in, const int* in_sizes, int n_in,
                              void* d_out, int out_size, void* d_ws, size_t ws_size,
                              hipStream_t stream) {
  const float* jp  = (const float*)d_in[0];
  const float* jv  = (const float*)d_in[1];
  const int*   adj = (const int*)d_in[2];
  const float* eW  = (const float*)d_in[3];
  const float* eB  = (const float*)d_in[4];
  const float* pE  = (const float*)d_in[5];
  const float* Wq  = (const float*)d_in[6];  const float* bq = (const float*)d_in[7];
  const float* Wk  = (const float*)d_in[8];  const float* bk = (const float*)d_in[9];
  const float* Wv  = (const float*)d_in[10]; const float* bv = (const float*)d_in[11];
  const float* Wo  = (const float*)d_in[12]; const float* bo = (const float*)d_in[13];
  const float* g1  = (const float*)d_in[14]; const float* be1 = (const float*)d_in[15];
  const float* g2  = (const float*)d_in[16]; const float* be2 = (const float*)d_in[17];
  const float* W1  = (const float*)d_in[18]; const float* b1 = (const float*)d_in[19];
  const float* W2  = (const float*)d_in[20]; const float* b2 = (const float*)d_in[21];

  bf16* ws    = (bf16*)d_ws;
  bf16* feats = ws;                    // 1048576
  bf16* embWT = ws + 1048576;          // 131072  [16*128 outcol][64 in]
  bf16* wqT   = embWT + 131072;        // 65536   [4][128 out][128 in]
  bf16* wkT   = wqT + 65536;
  bf16* wvT   = wkT + 65536;
  bf16* woT   = wvT + 65536;
  bf16* w1T   = woT + 65536;           // 262144  [4][512 f][128 in]
  bf16* w2T   = w1T + 262144;          // 262144  [4][128 out][512 f]

  prep_feats_k<<<(B_TOT * 64 + 255) / 256, 256, 0, stream>>>(jp, jv, feats);
  prep_tr_k<<<512, 256, 0, stream>>>(eW, embWT, 64, 128, 131072);
  prep_tr_k<<<256, 256, 0, stream>>>(Wq, wqT, 128, 128, 65536);
  prep_tr_k<<<256, 256, 0, stream>>>(Wk, wkT, 128, 128, 65536);
  prep_tr_k<<<256, 256, 0, stream>>>(Wv, wvT, 128, 128, 65536);
  prep_tr_k<<<256, 256, 0, stream>>>(Wo, woT, 128, 128, 65536);
  prep_tr_k<<<1024, 256, 0, stream>>>(W1, w1T, 128, 512, 262144);
  prep_tr_k<<<1024, 256, 0, stream>>>(W2, w2T, 512, 128, 262144);

  bot_main<<<NWGS, 512, 0, stream>>>(adj, eB, pE, bq, bk, bv, bo,
                                     g1, be1, g2, be2, b1, b2,
                                     feats, embWT, wqT, wkT, wvT, woT, w1T, w2T,
                                     (float*)d_out);
}

// Round 5
// 1158.578 us; speedup vs baseline: 1.6665x; 1.0383x over previous
//
#include <hip/hip_runtime.h>
#include <stdint.h>

typedef __bf16 bf16;
typedef bf16 bf16x8 __attribute__((ext_vector_type(8)));
typedef bf16 bf16x4 __attribute__((ext_vector_type(4)));
typedef float f32x4 __attribute__((ext_vector_type(4)));
typedef uint32_t u32;
typedef uint8_t u8;

#define B_TOT 16384
#define SWG 8
#define NWGS (B_TOT / SWG)   // 2048

__device__ __forceinline__ f32x4 mfma32(bf16x8 a, bf16x8 b, f32x4 c) {
  return __builtin_amdgcn_mfma_f32_16x16x32_bf16(a, b, c, 0, 0, 0);
}
__device__ __forceinline__ bf16x8 zero8() {
  bf16x8 v;
#pragma unroll
  for (int j = 0; j < 8; j++) v[j] = (bf16)0.f;
  return v;
}

// ordering fence between same-wave LDS store->load (round-1-verified pattern)
__device__ __forceinline__ void lds_fence() {
  __builtin_amdgcn_sched_barrier(0);
  asm volatile("s_waitcnt lgkmcnt(0)" ::: "memory");
  __builtin_amdgcn_sched_barrier(0);
}

// ---- raw slot barriers (T4: counted vmcnt keeps this slot's stage in flight) ----
__device__ __forceinline__ void bar_lg() {   // nothing pending for next slot
  __builtin_amdgcn_sched_barrier(0);
  asm volatile("s_waitcnt lgkmcnt(0)" ::: "memory");
  __builtin_amdgcn_s_barrier();
  __builtin_amdgcn_sched_barrier(0);
}
__device__ __forceinline__ void bar_v0() {   // drain all (idle-issue slot)
  __builtin_amdgcn_sched_barrier(0);
  asm volatile("s_waitcnt vmcnt(0) lgkmcnt(0)" ::: "memory");
  __builtin_amdgcn_s_barrier();
  __builtin_amdgcn_sched_barrier(0);
}
__device__ __forceinline__ void bar_v2() {   // keep newest stage (2 loads) in flight
  __builtin_amdgcn_sched_barrier(0);
  asm volatile("s_waitcnt vmcnt(2) lgkmcnt(0)" ::: "memory");
  __builtin_amdgcn_s_barrier();
  __builtin_amdgcn_sched_barrier(0);
}

// Stage one [128 rows x 128 bytes] weight K-half (16KB) into an LDS buffer.
// Swizzle applied on the GLOBAL source address (byte ^ ((row&7)<<4)); the
// linear LDS image is then the swizzled layout; reads apply the same XOR.
// Issued at slot END (sched_barrier-pinned) so vmcnt(2) preserves exactly it.
__device__ __forceinline__ void stage16(const u8* __restrict__ src, int rowstride, int colbase,
                                        u8* dst, int tid) {
  __builtin_amdgcn_sched_barrier(0);
#pragma unroll
  for (int rr = 0; rr < 2; ++rr) {
    u32 o = (u32)(rr * 512 + tid) * 16u;
    u32 row = o >> 7, cb = o & 0x7Fu;
    const u8* s = src + (size_t)row * (size_t)rowstride + (size_t)colbase
                      + (size_t)(cb ^ ((row & 7u) << 4));
    __builtin_amdgcn_global_load_lds((const __attribute__((address_space(1))) u32*)s,
                                     (__attribute__((address_space(3))) u32*)(dst + o),
                                     16, 0, 0);
  }
}

// scalar store into swizzled row-major [32 rows][128 cols] bf16 tile
__device__ __forceinline__ void st_row(u8* base, int row, int col, bf16 v) {
  *(bf16*)(base + (u32)(row * 256) + (u32)((2 * col) ^ ((row & 7) << 4))) = v;
}

// A-fragments (2 samples, full K=128) from swizzled row-major tile (verified r1)
__device__ __forceinline__ void loadA_rm(const u8* R, int g, int c, bf16x8 a[2][4]) {
  const u32 sw = (u32)(c & 7) << 4;
#pragma unroll
  for (int mt = 0; mt < 2; ++mt)
#pragma unroll
    for (int ks = 0; ks < 4; ++ks)
      a[mt][ks] = *(const bf16x8*)(R + (u32)((mt * 16 + c) * 256)
                                     + (((u32)(ks * 64 + g * 16)) ^ sw));
}

// acc[2][4] += A-half @ W-half. Wb = 16KB staged half (rows=outcols, 128B k-rows,
// swizzled). khalf selects the A-frag ks-pair. Wave covers outcols nh*64..+63.
__device__ __forceinline__ void gemm_half(const u8* Wb, int khalf, const bf16x8 a[2][4],
                                          f32x4 acc[2][4], int nh, int g, int c) {
  const u32 sw = (u32)(c & 7) << 4;
#pragma unroll
  for (int ksl = 0; ksl < 2; ++ksl) {
    int ks = khalf * 2 + ksl;
#pragma unroll
    for (int nt = 0; nt < 4; ++nt) {
      bf16x8 b = *(const bf16x8*)(Wb + (u32)((nh * 64 + nt * 16 + c) * 128)
                                     + (((u32)(ksl * 64 + g * 16)) ^ sw));
      acc[0][nt] = mfma32(a[0][ks], b, acc[0][nt]);
      acc[1][nt] = mfma32(a[1][ks], b, acc[1][nt]);
    }
  }
}

// C-fragment epilogue -> swizzled row-major tile, scalar stores (verified r1)
template <bool RELU>
__device__ __forceinline__ void epi_rm(const f32x4 acc[2][4], const float* __restrict__ bias,
                                       u8* Rdst, int nh, int g, int c) {
#pragma unroll
  for (int nt = 0; nt < 4; ++nt) {
    int col = nh * 64 + nt * 16 + c;
    float bb = bias[col];
#pragma unroll
    for (int mt = 0; mt < 2; ++mt)
#pragma unroll
      for (int r = 0; r < 4; ++r) {
        float v = acc[mt][nt][r] + bb;
        if (RELU) v = fmaxf(v, 0.f);
        st_row(Rdst, mt * 16 + 4 * g + r, col, (bf16)v);
      }
  }
}

__device__ __forceinline__ void ln_part(const f32x4 x[2][4], float sS[2][4], float sS2[2][4]) {
#pragma unroll
  for (int mt = 0; mt < 2; ++mt) {
    f32x4 a = {0.f, 0.f, 0.f, 0.f}, b = {0.f, 0.f, 0.f, 0.f};
#pragma unroll
    for (int nt = 0; nt < 4; ++nt) { a += x[mt][nt]; b += x[mt][nt] * x[mt][nt]; }
#pragma unroll
    for (int r = 0; r < 4; ++r) {
      float s = a[r], s2 = b[r];
#pragma unroll
      for (int off = 1; off < 16; off <<= 1) { s += __shfl_xor(s, off); s2 += __shfl_xor(s2, off); }
      sS[mt][r] = s; sS2[mt][r] = s2;
    }
  }
}

__global__ void __launch_bounds__(512, 2)
bot_main(const int* __restrict__ adj,
         const float* __restrict__ embB, const float* __restrict__ posE,
         const float* __restrict__ pbq, const float* __restrict__ pbk,
         const float* __restrict__ pbv, const float* __restrict__ pbo,
         const float* __restrict__ l1g, const float* __restrict__ l1b,
         const float* __restrict__ l2g, const float* __restrict__ l2b,
         const float* __restrict__ pb1, const float* __restrict__ pb2,
         const bf16* __restrict__ feats, const bf16* __restrict__ embWT,
         const bf16* __restrict__ wqT, const bf16* __restrict__ wkT,
         const bf16* __restrict__ wvT, const bf16* __restrict__ woT,
         const bf16* __restrict__ w1T, const bf16* __restrict__ w2T,
         float* __restrict__ out) {
  __shared__ u8 smem[163840];
  const int tid = threadIdx.x;
  const int w = tid >> 6, lane = tid & 63, g = lane >> 4, c = lane & 15;
  const int p = w >> 1, nh = w & 1;           // pair index, N-half
  const int S0 = blockIdx.x * SWG;
  const u32 sw = (u32)(c & 7) << 4;

  // activations: 24KB per pair (RA = h / vt / h2 time-shared; Rq; Rk)
  u8* pairb = smem + p * 24576;
  u8* RA = pairb;            // h (rm swizzled) -> vt (cm) -> h2 (rm swizzled)
  u8* Rq = pairb + 8192;     // q / P / O / U (row-major swizzled)
  u8* Rk = pairb + 16384;    // k (rm swizzled); LN scratch at base when k dead
  // weights: 4 x 16KB FIFO buffers
  u8* WB0 = smem + 98304;
  u8* WB1 = smem + 114688;
  u8* WB2 = smem + 131072;
  u8* WB3 = smem + 147456;
  float* scr = (float*)Rk;

  float maskr[4];
#pragma unroll
  for (int r = 0; r < 4; ++r) {
    int n = 4 * g + r;
    maskr[r] = (adj[n * 16 + c] != 0 || n == c) ? 0.f : -1e9f;
  }

  // ---------------- embed (WG-cooperative, transient x0 in LDS) ----------------
  {
    float* x0 = (float*)smem;  // [8 samples][2048] = 64KB (within activation area)
    f32x4 ea[16] = {};
    bf16x8 af[2];
#pragma unroll
    for (int ks = 0; ks < 2; ++ks)
      af[ks] = *(const bf16x8*)(feats + (size_t)(S0 + (c & 7)) * 64 + ks * 32 + g * 8);
#pragma unroll
    for (int nt = 0; nt < 16; ++nt) {
#pragma unroll
      for (int ks = 0; ks < 2; ++ks) {
        bf16x8 bw = *(const bf16x8*)(embWT + (size_t)(w * 256 + nt * 16 + c) * 64 + ks * 32 + g * 8);
        ea[nt] = mfma32(af[ks], bw, ea[nt]);
      }
    }
    if (g < 2) {
#pragma unroll
      for (int nt = 0; nt < 16; ++nt)
#pragma unroll
        for (int r = 0; r < 4; ++r)
          x0[(4 * g + r) * 2048 + w * 256 + nt * 16 + c] = ea[nt][r];
    }
  }
  __syncthreads();

  f32x4 x[2][4];
  {
    const float* x0 = (const float*)smem;
#pragma unroll
    for (int nt = 0; nt < 4; ++nt)
#pragma unroll
      for (int r = 0; r < 4; ++r) {
        int n = 4 * g + r, d = nh * 64 + nt * 16 + c;
        float eb = embB[n * 128 + d] + posE[n * 128 + d];
#pragma unroll
        for (int mt = 0; mt < 2; ++mt)
          x[mt][nt][r] = x0[(2 * p + mt) * 2048 + n * 128 + d] + eb;
      }
  }
  __syncthreads();

  bf16x8 Ah[2][4], Ah2[2][4], Au[2][4];

  // ------- layers: 28-slot schedule, lag-2 staging, counted-vmcnt barriers -------
#pragma unroll 1
  for (int l = 0; l < 4; ++l) {
    const u8* Wq_l = (const u8*)(wqT + (size_t)l * 16384);
    const u8* Wk_l = (const u8*)(wkT + (size_t)l * 16384);
    const u8* Wv_l = (const u8*)(wvT + (size_t)l * 16384);
    const u8* Wo_l = (const u8*)(woT + (size_t)l * 16384);
    const u8* W1_l = (const u8*)(w1T + (size_t)l * 65536);
    const u8* W2_l = (const u8*)(w2T + (size_t)l * 65536);

    float sS[2][4], sS2[2][4], mean[2][4], rstd[2][4];

    // s0: LN1 partials | issue Q-h0 -> B0
    ln_part(x, sS, sS2);
    if (c == 0) {
#pragma unroll
      for (int mt = 0; mt < 2; ++mt)
#pragma unroll
        for (int r = 0; r < 4; ++r) {
          int row = mt * 16 + 4 * g + r;
          scr[(row * 2 + nh) * 2 + 0] = sS[mt][r];
          scr[(row * 2 + nh) * 2 + 1] = sS2[mt][r];
        }
    }
    stage16(Wq_l, 256, 0, WB0, tid);
    bar_lg();

    // s1: LN1 combine + h store (RA) | issue Q-h1 -> B1
#pragma unroll
    for (int mt = 0; mt < 2; ++mt)
#pragma unroll
      for (int r = 0; r < 4; ++r) {
        int row = mt * 16 + 4 * g + r;
        float s = sS[mt][r] + scr[(row * 2 + (1 - nh)) * 2 + 0];
        float s2 = sS2[mt][r] + scr[(row * 2 + (1 - nh)) * 2 + 1];
        float mu = s * (1.f / 128.f);
        float va = s2 * (1.f / 128.f) - mu * mu;
        mean[mt][r] = mu; rstd[mt][r] = rsqrtf(va + 1e-5f);
      }
#pragma unroll
    for (int nt = 0; nt < 4; ++nt) {
      int col = nh * 64 + nt * 16 + c;
      float gg = l1g[l * 128 + col], bb = l1b[l * 128 + col];
#pragma unroll
      for (int mt = 0; mt < 2; ++mt)
#pragma unroll
        for (int r = 0; r < 4; ++r)
          st_row(RA, mt * 16 + 4 * g + r, col,
                 (bf16)((x[mt][nt][r] - mean[mt][r]) * rstd[mt][r] * gg + bb));
    }
    stage16(Wq_l, 256, 128, WB1, tid);
    bar_v2();

    f32x4 acc[2][4];
    // s2: loadA(h); Q-gemm h0 (B0) | issue K-h0 -> B2
    loadA_rm(RA, g, c, Ah);
#pragma unroll
    for (int mt = 0; mt < 2; ++mt)
#pragma unroll
      for (int nt = 0; nt < 4; ++nt) acc[mt][nt] = (f32x4){0.f, 0.f, 0.f, 0.f};
    gemm_half(WB0, 0, Ah, acc, nh, g, c);
    stage16(Wk_l, 256, 0, WB2, tid);
    bar_v2();

    // s3: Q-gemm h1 (B1) + q epi | issue K-h1 -> B3
    gemm_half(WB1, 1, Ah, acc, nh, g, c);
    epi_rm<false>(acc, pbq + l * 128, Rq, nh, g, c);
    stage16(Wk_l, 256, 128, WB3, tid);
    bar_v2();

    // s4: K-gemm h0 (B2) | issue V-h0 -> B0
#pragma unroll
    for (int mt = 0; mt < 2; ++mt)
#pragma unroll
      for (int nt = 0; nt < 4; ++nt) acc[mt][nt] = (f32x4){0.f, 0.f, 0.f, 0.f};
    gemm_half(WB2, 0, Ah, acc, nh, g, c);
    stage16(Wv_l, 256, 0, WB0, tid);
    bar_v2();

    // s5: K-gemm h1 (B3) + k epi | issue V-h1 -> B1
    gemm_half(WB3, 1, Ah, acc, nh, g, c);
    epi_rm<false>(acc, pbk + l * 128, Rk, nh, g, c);
    stage16(Wv_l, 256, 128, WB1, tid);
    bar_v2();

    // s6: V-gemm h0 (B0) | no issue -> drain
#pragma unroll
    for (int mt = 0; mt < 2; ++mt)
#pragma unroll
      for (int nt = 0; nt < 4; ++nt) acc[mt][nt] = (f32x4){0.f, 0.f, 0.f, 0.f};
    gemm_half(WB0, 0, Ah, acc, nh, g, c);
    bar_v0();

    // s7: V-gemm h1 (B1) + v epi TRANSPOSED (cm vt over RA, h dead) | issue O-h0 -> B2
    gemm_half(WB1, 1, Ah, acc, nh, g, c);
#pragma unroll
    for (int nt = 0; nt < 4; ++nt) {
      int col = nh * 64 + nt * 16 + c;
      float bb = pbv[l * 128 + col];
#pragma unroll
      for (int mt = 0; mt < 2; ++mt) {
        bf16x4 pk;
#pragma unroll
        for (int r = 0; r < 4; ++r) pk[r] = (bf16)(acc[mt][nt][r] + bb);
        *(bf16x4*)(RA + mt * 4096 + col * 32 + g * 8) = pk;
      }
    }
    stage16(Wo_l, 256, 0, WB2, tid);
    bar_lg();

    // s8: ATTENTION (4 heads, both samples; r4-verified paths) | issue O-h1 -> B3
    {
      const f32x4 zz = {0.f, 0.f, 0.f, 0.f};
#pragma unroll 1
      for (int hh = 0; hh < 4; ++hh) {
        const int gh = nh * 4 + hh;
        bf16x8 qf[2], kf[2];
#pragma unroll
        for (int mt = 0; mt < 2; ++mt) {
          if (g < 2) {
            qf[mt] = *(const bf16x8*)(Rq + (u32)((mt * 16 + c) * 256)
                                         + (((u32)(gh * 32 + g * 16)) ^ sw));
            kf[mt] = *(const bf16x8*)(Rk + (u32)((mt * 16 + c) * 256)
                                         + (((u32)(gh * 32 + g * 16)) ^ sw));
          } else { qf[mt] = zero8(); kf[mt] = zero8(); }
        }
        f32x4 sc[2];
        sc[0] = mfma32(qf[0], kf[0], zz);
        sc[1] = mfma32(qf[1], kf[1], zz);
        float pr[2][4], mx[2][4], sm[2][4];
#pragma unroll
        for (int mt = 0; mt < 2; ++mt)
#pragma unroll
          for (int r = 0; r < 4; ++r) { pr[mt][r] = sc[mt][r] * 0.25f + maskr[r]; mx[mt][r] = pr[mt][r]; }
#pragma unroll
        for (int off = 1; off < 16; off <<= 1)
#pragma unroll
          for (int mt = 0; mt < 2; ++mt)
#pragma unroll
            for (int r = 0; r < 4; ++r) mx[mt][r] = fmaxf(mx[mt][r], __shfl_xor(mx[mt][r], off));
#pragma unroll
        for (int mt = 0; mt < 2; ++mt)
#pragma unroll
          for (int r = 0; r < 4; ++r) { pr[mt][r] = __expf(pr[mt][r] - mx[mt][r]); sm[mt][r] = pr[mt][r]; }
#pragma unroll
        for (int off = 1; off < 16; off <<= 1)
#pragma unroll
          for (int mt = 0; mt < 2; ++mt)
#pragma unroll
            for (int r = 0; r < 4; ++r) sm[mt][r] += __shfl_xor(sm[mt][r], off);
        // P over dead Q head-block (scalar st_row, same-wave cols)
#pragma unroll
        for (int mt = 0; mt < 2; ++mt)
#pragma unroll
          for (int r = 0; r < 4; ++r)
            st_row(Rq, mt * 16 + 4 * g + r, gh * 16 + c,
                   (bf16)(pr[mt][r] * __fdividef(1.f, sm[mt][r])));
        lds_fence();
        bf16x8 pa[2], vf[2];
#pragma unroll
        for (int mt = 0; mt < 2; ++mt) {
          if (g < 2) {
            pa[mt] = *(const bf16x8*)(Rq + (u32)((mt * 16 + c) * 256)
                                         + (((u32)(gh * 32 + g * 16)) ^ sw));
            vf[mt] = *(const bf16x8*)(RA + mt * 4096 + gh * 512 + c * 32 + g * 16);
          } else { pa[mt] = zero8(); vf[mt] = zero8(); }
        }
        f32x4 oo[2];
        oo[0] = mfma32(pa[0], vf[0], zz);
        oo[1] = mfma32(pa[1], vf[1], zz);
#pragma unroll
        for (int mt = 0; mt < 2; ++mt)
#pragma unroll
          for (int r = 0; r < 4; ++r)
            st_row(Rq, mt * 16 + 4 * g + r, gh * 16 + c, (bf16)oo[mt][r]);
      }
    }
    stage16(Wo_l, 256, 128, WB3, tid);
    bar_v2();

    // s9: loadA(O); O-proj h0 (B2) into x | no issue -> drain
    loadA_rm(Rq, g, c, Ah);
    gemm_half(WB2, 0, Ah, x, nh, g, c);
    bar_v0();

    // s10: O-proj h1 (B3) + bo + LN2 partials | issue W1c0-h0 -> B0
    gemm_half(WB3, 1, Ah, x, nh, g, c);
#pragma unroll
    for (int nt = 0; nt < 4; ++nt) {
      float bb = pbo[l * 128 + nh * 64 + nt * 16 + c];
#pragma unroll
      for (int mt = 0; mt < 2; ++mt)
#pragma unroll
        for (int r = 0; r < 4; ++r) x[mt][nt][r] += bb;
    }
    ln_part(x, sS, sS2);
    if (c == 0) {
#pragma unroll
      for (int mt = 0; mt < 2; ++mt)
#pragma unroll
        for (int r = 0; r < 4; ++r) {
          int row = mt * 16 + 4 * g + r;
          scr[(row * 2 + nh) * 2 + 0] = sS[mt][r];
          scr[(row * 2 + nh) * 2 + 1] = sS2[mt][r];
        }
    }
    stage16(W1_l, 256, 0, WB0, tid);
    bar_lg();

    // s11: LN2 combine + h2 store (RA, vt dead) | issue W1c0-h1 -> B1
#pragma unroll
    for (int mt = 0; mt < 2; ++mt)
#pragma unroll
      for (int r = 0; r < 4; ++r) {
        int row = mt * 16 + 4 * g + r;
        float s = sS[mt][r] + scr[(row * 2 + (1 - nh)) * 2 + 0];
        float s2 = sS2[mt][r] + scr[(row * 2 + (1 - nh)) * 2 + 1];
        float mu = s * (1.f / 128.f);
        float va = s2 * (1.f / 128.f) - mu * mu;
        mean[mt][r] = mu; rstd[mt][r] = rsqrtf(va + 1e-5f);
      }
#pragma unroll
    for (int nt = 0; nt < 4; ++nt) {
      int col = nh * 64 + nt * 16 + c;
      float gg = l2g[l * 128 + col], bb = l2b[l * 128 + col];
#pragma unroll
      for (int mt = 0; mt < 2; ++mt)
#pragma unroll
        for (int r = 0; r < 4; ++r)
          st_row(RA, mt * 16 + 4 * g + r, col,
                 (bf16)((x[mt][nt][r] - mean[mt][r]) * rstd[mt][r] * gg + bb));
    }
    stage16(W1_l, 256, 128, WB1, tid);
    bar_v2();

    // ---------------- FFN: 4 slots per chunk ----------------
#pragma unroll 1
    for (int fc = 0; fc < 4; ++fc) {
      f32x4 uacc[2][4];
#pragma unroll
      for (int mt = 0; mt < 2; ++mt)
#pragma unroll
        for (int nt = 0; nt < 4; ++nt) uacc[mt][nt] = (f32x4){0.f, 0.f, 0.f, 0.f};
      // sU0: (fc==0: loadA h2); U-gemm h0 (B0) | issue W2cfc-h0 -> B2
      if (fc == 0) loadA_rm(RA, g, c, Ah2);
      gemm_half(WB0, 0, Ah2, uacc, nh, g, c);
      stage16(W2_l, 1024, fc * 256, WB2, tid);
      bar_v2();
      // sU1: U-gemm h1 (B1) + relu epi -> Rq | issue W2cfc-h1 -> B3
      gemm_half(WB1, 1, Ah2, uacc, nh, g, c);
      epi_rm<true>(uacc, pb1 + l * 512 + fc * 128, Rq, nh, g, c);
      stage16(W2_l, 1024, fc * 256 + 128, WB3, tid);
      bar_v2();
      // sY0: loadA(U); Y-gemm h0 (B2) into x | issue W1c(fc+1)-h0 -> B0 (fc<3)
      loadA_rm(Rq, g, c, Au);
      gemm_half(WB2, 0, Au, x, nh, g, c);
      if (fc < 3) { stage16(W1_l + (fc + 1) * 32768, 256, 0, WB0, tid); bar_v2(); }
      else bar_v0();
      // sY1: Y-gemm h1 (B3) into x | issue W1c(fc+1)-h1 -> B1 (fc<3)
      gemm_half(WB3, 1, Au, x, nh, g, c);
      if (fc < 3) { stage16(W1_l + (fc + 1) * 32768, 256, 128, WB1, tid); bar_v2(); }
      else {
#pragma unroll
        for (int nt = 0; nt < 4; ++nt) {
          float bb = pb2[l * 128 + nh * 64 + nt * 16 + c];
#pragma unroll
          for (int mt = 0; mt < 2; ++mt)
#pragma unroll
            for (int r = 0; r < 4; ++r) x[mt][nt][r] += bb;
        }
        bar_lg();
      }
    }
  }

  // ---------------- output: LDS bounce -> fully coalesced fp32 stores ----------------
#pragma unroll
  for (int nt = 0; nt < 4; ++nt) {
    int col = nh * 64 + nt * 16 + c;
#pragma unroll
    for (int mt = 0; mt < 2; ++mt)
      *(f32x4*)(pairb + mt * 8192 + col * 64 + g * 16) = x[mt][nt];
  }
  bar_lg();
  {
    const int smp = S0 + 2 * p + nh;
    const u8* src = pairb + nh * 8192;
#pragma unroll
    for (int it = 0; it < 8; ++it) {
      int n = it * 2 + (lane >> 5);
      int slot = lane & 31;
      f32x4 v;
#pragma unroll
      for (int e = 0; e < 4; ++e)
        v[e] = *(const float*)(src + (u32)((slot * 4 + e) * 64 + n * 4));
      *(f32x4*)(out + (size_t)smp * 2048 + n * 128 + slot * 4) = v;
    }
  }
}

// ---------------- prep kernels ----------------
__global__ void prep_feats_k(const float* __restrict__ pos, const float* __restrict__ vel,
                             bf16* __restrict__ feats) {
  int i = blockIdx.x * 256 + threadIdx.x;
  if (i >= B_TOT * 64) return;
  int b = i >> 6, k = i & 63;
  float v = (k < 32) ? pos[b * 32 + k] : vel[b * 32 + (k - 32)];
  feats[i] = (bf16)v;
}

// dst[m][cc][rr] = (bf16) src[m][rr][cc]; src is [mats][R][C] fp32
__global__ void prep_tr_k(const float* __restrict__ src, bf16* __restrict__ dst,
                          int R, int C, int total) {
  int i = blockIdx.x * 256 + threadIdx.x;
  if (i >= total) return;
  int rc = R * C;
  int m = i / rc, rem = i % rc;
  int cc = rem / R, rr = rem % R;
  dst[i] = (bf16)src[(size_t)m * rc + rr * C + cc];
}

extern "C" void kernel_launch(void* const* d_in, const int* in_sizes, int n_in,
                              void* d_out, int out_size, void* d_ws, size_t ws_size,
                              hipStream_t stream) {
  const float* jp  = (const float*)d_in[0];
  const float* jv  = (const float*)d_in[1];
  const int*   adj = (const int*)d_in[2];
  const float* eW  = (const float*)d_in[3];
  const float* eB  = (const float*)d_in[4];
  const float* pE  = (const float*)d_in[5];
  const float* Wq  = (const float*)d_in[6];  const float* bq = (const float*)d_in[7];
  const float* Wk  = (const float*)d_in[8];  const float* bk = (const float*)d_in[9];
  const float* Wv  = (const float*)d_in[10]; const float* bv = (const float*)d_in[11];
  const float* Wo  = (const float*)d_in[12]; const float* bo = (const float*)d_in[13];
  const float* g1  = (const float*)d_in[14]; const float* be1 = (const float*)d_in[15];
  const float* g2  = (const float*)d_in[16]; const float* be2 = (const float*)d_in[17];
  const float* W1  = (const float*)d_in[18]; const float* b1 = (const float*)d_in[19];
  const float* W2  = (const float*)d_in[20]; const float* b2 = (const float*)d_in[21];

  bf16* ws    = (bf16*)d_ws;
  bf16* feats = ws;                    // 1048576
  bf16* embWT = ws + 1048576;          // 131072  [16*128 outcol][64 in]
  bf16* wqT   = embWT + 131072;        // 65536   [4][128 out][128 in]
  bf16* wkT   = wqT + 65536;
  bf16* wvT   = wkT + 65536;
  bf16* woT   = wvT + 65536;
  bf16* w1T   = woT + 65536;           // 262144  [4][512 f][128 in]
  bf16* w2T   = w1T + 262144;          // 262144  [4][128 out][512 f]

  prep_feats_k<<<(B_TOT * 64 + 255) / 256, 256, 0, stream>>>(jp, jv, feats);
  prep_tr_k<<<512, 256, 0, stream>>>(eW, embWT, 64, 128, 131072);
  prep_tr_k<<<256, 256, 0, stream>>>(Wq, wqT, 128, 128, 65536);
  prep_tr_k<<<256, 256, 0, stream>>>(Wk, wkT, 128, 128, 65536);
  prep_tr_k<<<256, 256, 0, stream>>>(Wv, wvT, 128, 128, 65536);
  prep_tr_k<<<256, 256, 0, stream>>>(Wo, woT, 128, 128, 65536);
  prep_tr_k<<<1024, 256, 0, stream>>>(W1, w1T, 128, 512, 262144);
  prep_tr_k<<<1024, 256, 0, stream>>>(W2, w2T, 512, 128, 262144);

  bot_main<<<NWGS, 512, 0, stream>>>(adj, eB, pE, bq, bk, bv, bo,
                                     g1, be1, g2, be2, b1, b2,
                                     feats, embWT, wqT, wkT, wvT, woT, w1T, w2T,
                                     (float*)d_out);
}

// Round 6
// 1046.519 us; speedup vs baseline: 1.8449x; 1.1071x over previous
//
#include <hip/hip_runtime.h>
#include <stdint.h>

typedef __bf16 bf16;
typedef bf16 bf16x8 __attribute__((ext_vector_type(8)));
typedef bf16 bf16x4 __attribute__((ext_vector_type(4)));
typedef float f32x4 __attribute__((ext_vector_type(4)));
typedef uint32_t u32;
typedef uint8_t u8;

#define B_TOT 16384
#define SWG 8
#define NWGS (B_TOT / SWG)   // 2048

__device__ __forceinline__ f32x4 mfma32(bf16x8 a, bf16x8 b, f32x4 c) {
  return __builtin_amdgcn_mfma_f32_16x16x32_bf16(a, b, c, 0, 0, 0);
}
__device__ __forceinline__ bf16x8 zero8() {
  bf16x8 v;
#pragma unroll
  for (int j = 0; j < 8; j++) v[j] = (bf16)0.f;
  return v;
}

// ---- raw slot barriers (T4: counted vmcnt keeps this slot's stage in flight) ----
__device__ __forceinline__ void bar_lg() {
  __builtin_amdgcn_sched_barrier(0);
  asm volatile("s_waitcnt lgkmcnt(0)" ::: "memory");
  __builtin_amdgcn_s_barrier();
  __builtin_amdgcn_sched_barrier(0);
}
__device__ __forceinline__ void bar_v0() {
  __builtin_amdgcn_sched_barrier(0);
  asm volatile("s_waitcnt vmcnt(0) lgkmcnt(0)" ::: "memory");
  __builtin_amdgcn_s_barrier();
  __builtin_amdgcn_sched_barrier(0);
}
__device__ __forceinline__ void bar_v2() {
  __builtin_amdgcn_sched_barrier(0);
  asm volatile("s_waitcnt vmcnt(2) lgkmcnt(0)" ::: "memory");
  __builtin_amdgcn_s_barrier();
  __builtin_amdgcn_sched_barrier(0);
}

// Stage one [128 rows x 128 bytes] weight K-half (16KB) into an LDS buffer.
// Swizzle on the GLOBAL source address (byte ^ ((row&7)<<4)); linear LDS image
// is the swizzled layout; reads apply the same XOR (weight tiles: &7).
__device__ __forceinline__ void stage16(const u8* __restrict__ src, int rowstride, int colbase,
                                        u8* dst, int tid) {
  __builtin_amdgcn_sched_barrier(0);
#pragma unroll
  for (int rr = 0; rr < 2; ++rr) {
    u32 o = (u32)(rr * 512 + tid) * 16u;
    u32 row = o >> 7, cb = o & 0x7Fu;
    const u8* s = src + (size_t)row * (size_t)rowstride + (size_t)colbase
                      + (size_t)(cb ^ ((row & 7u) << 4));
    __builtin_amdgcn_global_load_lds((const __attribute__((address_space(1))) u32*)s,
                                     (__attribute__((address_space(3))) u32*)(dst + o),
                                     16, 0, 0);
  }
}

// scalar store into swizzled row-major [32 rows][128 cols] bf16 ACTIVATION tile
// (&15 swizzle: row bit 3 (=g of C-frag rows 4g+r+16mt) reaches the bank bits)
__device__ __forceinline__ void st_row(u8* base, int row, int col, bf16 v) {
  *(bf16*)(base + (u32)(row * 256) + (u32)((2 * col) ^ ((row & 15) << 4))) = v;
}

// A-fragments (2 samples, full K=128) from swizzled row-major activation tile
__device__ __forceinline__ void loadA_rm(const u8* R, int g, int c, bf16x8 a[2][4]) {
  const u32 sw = (u32)c << 4;   // (row&15)<<4 with row = mt*16+c
#pragma unroll
  for (int mt = 0; mt < 2; ++mt)
#pragma unroll
    for (int ks = 0; ks < 4; ++ks)
      a[mt][ks] = *(const bf16x8*)(R + (u32)((mt * 16 + c) * 256)
                                     + (((u32)(ks * 64 + g * 16)) ^ sw));
}

// acc[2][4] += A-half @ W-half (weight tile &7 swizzle). Wave covers outcols nh*64..+63.
__device__ __forceinline__ void gemm_half(const u8* Wb, int khalf, const bf16x8 a[2][4],
                                          f32x4 acc[2][4], int nh, int g, int c) {
  const u32 sw = (u32)(c & 7) << 4;
#pragma unroll
  for (int ksl = 0; ksl < 2; ++ksl) {
    int ks = khalf * 2 + ksl;
#pragma unroll
    for (int nt = 0; nt < 4; ++nt) {
      bf16x8 b = *(const bf16x8*)(Wb + (u32)((nh * 64 + nt * 16 + c) * 128)
                                     + (((u32)(ksl * 64 + g * 16)) ^ sw));
      acc[0][nt] = mfma32(a[0][ks], b, acc[0][nt]);
      acc[1][nt] = mfma32(a[1][ks], b, acc[1][nt]);
    }
  }
}

// C-fragment epilogue -> swizzled row-major tile, scalar stores
template <bool RELU>
__device__ __forceinline__ void epi_rm(const f32x4 acc[2][4], const float* __restrict__ bias,
                                       u8* Rdst, int nh, int g, int c) {
#pragma unroll
  for (int nt = 0; nt < 4; ++nt) {
    int col = nh * 64 + nt * 16 + c;
    float bb = bias[col];
#pragma unroll
    for (int mt = 0; mt < 2; ++mt)
#pragma unroll
      for (int r = 0; r < 4; ++r) {
        float v = acc[mt][nt][r] + bb;
        if (RELU) v = fmaxf(v, 0.f);
        st_row(Rdst, mt * 16 + 4 * g + r, col, (bf16)v);
      }
  }
}

// pack 4 f32 -> two u32 of bf16 pairs (elem order [v0,v1|v2,v3])
__device__ __forceinline__ void pack4(const f32x4 v, u32& w0, u32& w1) {
  union { bf16 h[2]; u32 u; } t0, t1;
  t0.h[0] = (bf16)v[0]; t0.h[1] = (bf16)v[1];
  t1.h[0] = (bf16)v[2]; t1.h[1] = (bf16)v[3];
  w0 = t0.u; w1 = t1.u;
}

// R: C-frag of 16x16 block T (lane(g,c) rows 4g+r, col c, packed w0/w1)
//  -> A/B-frag of T^T: lane(g<2,c) holds T[8g+e][c], e=0..7; g>=2 zero.
// Valid when T's ROW axis is the next mfma contraction axis.
__device__ __forceinline__ bf16x8 Rfrag(u32 w0, u32 w1, int g, int c) {
  int s0 = 32 * g + c;         // source lane for elems 0..3 (valid g<2)
  int s1 = 32 * g + 16 + c;    // source lane for elems 4..7
  u32 a0 = (u32)__shfl((int)w0, s0);
  u32 a1 = (u32)__shfl((int)w1, s0);
  u32 a2 = (u32)__shfl((int)w0, s1);
  u32 a3 = (u32)__shfl((int)w1, s1);
  union { u32 u[4]; bf16x8 v; } r;
  bool ok = (g < 2);
  r.u[0] = ok ? a0 : 0u; r.u[1] = ok ? a1 : 0u;
  r.u[2] = ok ? a2 : 0u; r.u[3] = ok ? a3 : 0u;
  return r.v;
}

__device__ __forceinline__ void ln_part(const f32x4 x[2][4], float sS[2][4], float sS2[2][4]) {
#pragma unroll
  for (int mt = 0; mt < 2; ++mt) {
    f32x4 a = {0.f, 0.f, 0.f, 0.f}, b = {0.f, 0.f, 0.f, 0.f};
#pragma unroll
    for (int nt = 0; nt < 4; ++nt) { a += x[mt][nt]; b += x[mt][nt] * x[mt][nt]; }
#pragma unroll
    for (int r = 0; r < 4; ++r) {
      float s = a[r], s2 = b[r];
#pragma unroll
      for (int off = 1; off < 16; off <<= 1) { s += __shfl_xor(s, off); s2 += __shfl_xor(s2, off); }
      sS[mt][r] = s; sS2[mt][r] = s2;
    }
  }
}

__global__ void __launch_bounds__(512, 2)
bot_main(const int* __restrict__ adj,
         const float* __restrict__ embB, const float* __restrict__ posE,
         const float* __restrict__ pbq, const float* __restrict__ pbk,
         const float* __restrict__ pbv, const float* __restrict__ pbo,
         const float* __restrict__ l1g, const float* __restrict__ l1b,
         const float* __restrict__ l2g, const float* __restrict__ l2b,
         const float* __restrict__ pb1, const float* __restrict__ pb2,
         const bf16* __restrict__ feats, const bf16* __restrict__ embWT,
         const bf16* __restrict__ wqT, const bf16* __restrict__ wkT,
         const bf16* __restrict__ wvT, const bf16* __restrict__ woT,
         const bf16* __restrict__ w1T, const bf16* __restrict__ w2T,
         float* __restrict__ out) {
  __shared__ u8 smem[163840];
  const int tid = threadIdx.x;
  const int w = tid >> 6, lane = tid & 63, g = lane >> 4, c = lane & 15;
  const int p = w >> 1, nh = w & 1;           // pair index, N-half
  const int S0 = blockIdx.x * SWG;

  u8* pairb = smem + p * 24576;
  u8* RA = pairb;            // h -> h2 (row-major swizzled activation tiles)
  u8* Rq = pairb + 8192;     // q -> O-exchange -> U
  u8* Rk = pairb + 16384;    // k; LN scratch at base when k dead
  u8* WB0 = smem + 98304;    // 4 x 16KB weight FIFO
  u8* WB1 = smem + 114688;
  u8* WB2 = smem + 131072;
  u8* WB3 = smem + 147456;
  float* scr = (float*)Rk;

  // transposed mask for swapped-QK^T S^T layout: lane(g,c),r -> (n=c, m=4g+r)
  float maskT[4];
#pragma unroll
  for (int r = 0; r < 4; ++r) {
    int m = 4 * g + r;
    maskT[r] = (adj[c * 16 + m] != 0 || c == m) ? 0.f : -1e9f;
  }

  // ---------------- embed (WG-cooperative, transient x0 in LDS) ----------------
  {
    float* x0 = (float*)smem;  // [8 samples][2048]
    f32x4 ea[16] = {};
    bf16x8 af[2];
#pragma unroll
    for (int ks = 0; ks < 2; ++ks)
      af[ks] = *(const bf16x8*)(feats + (size_t)(S0 + (c & 7)) * 64 + ks * 32 + g * 8);
#pragma unroll
    for (int nt = 0; nt < 16; ++nt) {
#pragma unroll
      for (int ks = 0; ks < 2; ++ks) {
        bf16x8 bw = *(const bf16x8*)(embWT + (size_t)(w * 256 + nt * 16 + c) * 64 + ks * 32 + g * 8);
        ea[nt] = mfma32(af[ks], bw, ea[nt]);
      }
    }
    if (g < 2) {
#pragma unroll
      for (int nt = 0; nt < 16; ++nt)
#pragma unroll
        for (int r = 0; r < 4; ++r)
          x0[(4 * g + r) * 2048 + w * 256 + nt * 16 + c] = ea[nt][r];
    }
  }
  __syncthreads();

  f32x4 x[2][4];
  {
    const float* x0 = (const float*)smem;
#pragma unroll
    for (int nt = 0; nt < 4; ++nt)
#pragma unroll
      for (int r = 0; r < 4; ++r) {
        int n = 4 * g + r, d = nh * 64 + nt * 16 + c;
        float eb = embB[n * 128 + d] + posE[n * 128 + d];
#pragma unroll
        for (int mt = 0; mt < 2; ++mt)
          x[mt][nt][r] = x0[(2 * p + mt) * 2048 + n * 128 + d] + eb;
      }
  }
  __syncthreads();

  bf16x8 Ah[2][4], Ah2[2][4], Au[2][4];

  // ------- layers: 28-slot schedule, lag-2 staging, counted-vmcnt barriers -------
#pragma unroll 1
  for (int l = 0; l < 4; ++l) {
    const u8* Wq_l = (const u8*)(wqT + (size_t)l * 16384);
    const u8* Wk_l = (const u8*)(wkT + (size_t)l * 16384);
    const u8* Wv_l = (const u8*)(wvT + (size_t)l * 16384);
    const u8* Wo_l = (const u8*)(woT + (size_t)l * 16384);
    const u8* W1_l = (const u8*)(w1T + (size_t)l * 65536);
    const u8* W2_l = (const u8*)(w2T + (size_t)l * 65536);

    float sS[2][4], sS2[2][4], mean[2][4], rstd[2][4];

    // s0: LN1 partials | issue Q-h0 -> B0
    ln_part(x, sS, sS2);
    if (c == 0) {
#pragma unroll
      for (int mt = 0; mt < 2; ++mt)
#pragma unroll
        for (int r = 0; r < 4; ++r) {
          int row = mt * 16 + 4 * g + r;
          scr[(row * 2 + nh) * 2 + 0] = sS[mt][r];
          scr[(row * 2 + nh) * 2 + 1] = sS2[mt][r];
        }
    }
    stage16(Wq_l, 256, 0, WB0, tid);
    bar_lg();

    // s1: LN1 combine + h store | issue Q-h1 -> B1
#pragma unroll
    for (int mt = 0; mt < 2; ++mt)
#pragma unroll
      for (int r = 0; r < 4; ++r) {
        int row = mt * 16 + 4 * g + r;
        float s = sS[mt][r] + scr[(row * 2 + (1 - nh)) * 2 + 0];
        float s2 = sS2[mt][r] + scr[(row * 2 + (1 - nh)) * 2 + 1];
        float mu = s * (1.f / 128.f);
        float va = s2 * (1.f / 128.f) - mu * mu;
        mean[mt][r] = mu; rstd[mt][r] = rsqrtf(va + 1e-5f);
      }
#pragma unroll
    for (int nt = 0; nt < 4; ++nt) {
      int col = nh * 64 + nt * 16 + c;
      float gg = l1g[l * 128 + col], bb = l1b[l * 128 + col];
#pragma unroll
      for (int mt = 0; mt < 2; ++mt)
#pragma unroll
        for (int r = 0; r < 4; ++r)
          st_row(RA, mt * 16 + 4 * g + r, col,
                 (bf16)((x[mt][nt][r] - mean[mt][r]) * rstd[mt][r] * gg + bb));
    }
    stage16(Wq_l, 256, 128, WB1, tid);
    bar_v2();

    f32x4 acc[2][4];
    // s2: loadA(h); Q-gemm h0 (B0) | issue K-h0 -> B2
    loadA_rm(RA, g, c, Ah);
#pragma unroll
    for (int mt = 0; mt < 2; ++mt)
#pragma unroll
      for (int nt = 0; nt < 4; ++nt) acc[mt][nt] = (f32x4){0.f, 0.f, 0.f, 0.f};
    gemm_half(WB0, 0, Ah, acc, nh, g, c);
    stage16(Wk_l, 256, 0, WB2, tid);
    bar_v2();

    // s3: Q-gemm h1 (B1) + q epi | issue K-h1 -> B3
    gemm_half(WB1, 1, Ah, acc, nh, g, c);
    epi_rm<false>(acc, pbq + l * 128, Rq, nh, g, c);
    stage16(Wk_l, 256, 128, WB3, tid);
    bar_v2();

    // s4: K-gemm h0 (B2) | issue V-h0 -> B0
#pragma unroll
    for (int mt = 0; mt < 2; ++mt)
#pragma unroll
      for (int nt = 0; nt < 4; ++nt) acc[mt][nt] = (f32x4){0.f, 0.f, 0.f, 0.f};
    gemm_half(WB2, 0, Ah, acc, nh, g, c);
    stage16(Wv_l, 256, 0, WB0, tid);
    bar_v2();

    // s5: K-gemm h1 (B3) + k epi | issue V-h1 -> B1
    gemm_half(WB3, 1, Ah, acc, nh, g, c);
    epi_rm<false>(acc, pbk + l * 128, Rk, nh, g, c);
    stage16(Wv_l, 256, 128, WB1, tid);
    bar_v2();

    // s6: V-gemm h0 (B0) | no issue -> drain
#pragma unroll
    for (int mt = 0; mt < 2; ++mt)
#pragma unroll
      for (int nt = 0; nt < 4; ++nt) acc[mt][nt] = (f32x4){0.f, 0.f, 0.f, 0.f};
    gemm_half(WB0, 0, Ah, acc, nh, g, c);
    bar_v0();

    // s7: V-gemm h1 (B1); V -> IN-REGISTER PV A-frags via Rfrag | issue O-h0 -> B2
    bf16x8 Vf[2][4];
    gemm_half(WB1, 1, Ah, acc, nh, g, c);
#pragma unroll
    for (int nt = 0; nt < 4; ++nt) {
      float bb = pbv[l * 128 + nh * 64 + nt * 16 + c];
#pragma unroll
      for (int mt = 0; mt < 2; ++mt) {
        f32x4 v;
#pragma unroll
        for (int r = 0; r < 4; ++r) v[r] = acc[mt][nt][r] + bb;
        u32 w0, w1; pack4(v, w0, w1);
        Vf[mt][nt] = Rfrag(w0, w1, g, c);   // A-frag of V^T (block = head nt)
      }
    }
    stage16(Wo_l, 256, 0, WB2, tid);
    bar_lg();

    // s8: ATTENTION — swapped QK^T, in-register softmax/P/V, vector O stores
    //     | issue O-h1 -> B3
    {
      const f32x4 zz = {0.f, 0.f, 0.f, 0.f};
      const u32 swa = (u32)c << 4;
#pragma unroll
      for (int hh = 0; hh < 4; ++hh) {
        const int gh = nh * 4 + hh;
        bf16x8 qf[2], kf[2];
#pragma unroll
        for (int mt = 0; mt < 2; ++mt) {
          if (g < 2) {
            qf[mt] = *(const bf16x8*)(Rq + (u32)((mt * 16 + c) * 256)
                                         + (((u32)(gh * 32 + g * 16)) ^ swa));
            kf[mt] = *(const bf16x8*)(Rk + (u32)((mt * 16 + c) * 256)
                                         + (((u32)(gh * 32 + g * 16)) ^ swa));
          } else { qf[mt] = zero8(); kf[mt] = zero8(); }
        }
#pragma unroll
        for (int mt = 0; mt < 2; ++mt) {
          // S^T = K · Q^T : lane(g,c) rows m=4g+r, col n=c
          f32x4 st = mfma32(kf[mt], qf[mt], zz);
          float pr[4];
#pragma unroll
          for (int r = 0; r < 4; ++r) pr[r] = st[r] * 0.25f + maskT[r];
          float mx = fmaxf(fmaxf(pr[0], pr[1]), fmaxf(pr[2], pr[3]));
          mx = fmaxf(mx, __shfl_xor(mx, 16));
          mx = fmaxf(mx, __shfl_xor(mx, 32));
          float sm = 0.f;
#pragma unroll
          for (int r = 0; r < 4; ++r) { pr[r] = __expf(pr[r] - mx); sm += pr[r]; }
          sm += __shfl_xor(sm, 16);
          sm += __shfl_xor(sm, 32);
          float pinv = __fdividef(1.f, sm);
          f32x4 pv;
#pragma unroll
          for (int r = 0; r < 4; ++r) pv[r] = pr[r] * pinv;
          u32 w0, w1; pack4(pv, w0, w1);
          bf16x8 Pf = Rfrag(w0, w1, g, c);        // B-frag: P[n][m]
          f32x4 oo = mfma32(Vf[mt][hh], Pf, zz);  // O^T: rows d=4g+r, col n=c
          pack4(oo, w0, w1);
          bf16x8 Of = Rfrag(w0, w1, g, c);        // O[n=c][d-run]
          if (g < 2)
            *(bf16x8*)(Rq + (u32)((mt * 16 + c) * 256)
                          + (((u32)(gh * 32 + g * 16)) ^ swa)) = Of;  // over dead q
        }
      }
    }
    stage16(Wo_l, 256, 128, WB3, tid);
    bar_v2();

    // s9: loadA(O); O-proj h0 (B2) into x | no issue -> drain
    loadA_rm(Rq, g, c, Ah);
    gemm_half(WB2, 0, Ah, x, nh, g, c);
    bar_v0();

    // s10: O-proj h1 (B3) + bo + LN2 partials | issue W1c0-h0 -> B0
    gemm_half(WB3, 1, Ah, x, nh, g, c);
#pragma unroll
    for (int nt = 0; nt < 4; ++nt) {
      float bb = pbo[l * 128 + nh * 64 + nt * 16 + c];
#pragma unroll
      for (int mt = 0; mt < 2; ++mt)
#pragma unroll
        for (int r = 0; r < 4; ++r) x[mt][nt][r] += bb;
    }
    ln_part(x, sS, sS2);
    if (c == 0) {
#pragma unroll
      for (int mt = 0; mt < 2; ++mt)
#pragma unroll
        for (int r = 0; r < 4; ++r) {
          int row = mt * 16 + 4 * g + r;
          scr[(row * 2 + nh) * 2 + 0] = sS[mt][r];
          scr[(row * 2 + nh) * 2 + 1] = sS2[mt][r];
        }
    }
    stage16(W1_l, 256, 0, WB0, tid);
    bar_lg();

    // s11: LN2 combine + h2 store (RA) | issue W1c0-h1 -> B1
#pragma unroll
    for (int mt = 0; mt < 2; ++mt)
#pragma unroll
      for (int r = 0; r < 4; ++r) {
        int row = mt * 16 + 4 * g + r;
        float s = sS[mt][r] + scr[(row * 2 + (1 - nh)) * 2 + 0];
        float s2 = sS2[mt][r] + scr[(row * 2 + (1 - nh)) * 2 + 1];
        float mu = s * (1.f / 128.f);
        float va = s2 * (1.f / 128.f) - mu * mu;
        mean[mt][r] = mu; rstd[mt][r] = rsqrtf(va + 1e-5f);
      }
#pragma unroll
    for (int nt = 0; nt < 4; ++nt) {
      int col = nh * 64 + nt * 16 + c;
      float gg = l2g[l * 128 + col], bb = l2b[l * 128 + col];
#pragma unroll
      for (int mt = 0; mt < 2; ++mt)
#pragma unroll
        for (int r = 0; r < 4; ++r)
          st_row(RA, mt * 16 + 4 * g + r, col,
                 (bf16)((x[mt][nt][r] - mean[mt][r]) * rstd[mt][r] * gg + bb));
    }
    stage16(W1_l, 256, 128, WB1, tid);
    bar_v2();

    // ---------------- FFN: 4 slots per chunk (unchanged from r5) ----------------
#pragma unroll 1
    for (int fc = 0; fc < 4; ++fc) {
      f32x4 uacc[2][4];
#pragma unroll
      for (int mt = 0; mt < 2; ++mt)
#pragma unroll
        for (int nt = 0; nt < 4; ++nt) uacc[mt][nt] = (f32x4){0.f, 0.f, 0.f, 0.f};
      // sU0: (fc==0: loadA h2); U-gemm h0 (B0) | issue W2cfc-h0 -> B2
      if (fc == 0) loadA_rm(RA, g, c, Ah2);
      gemm_half(WB0, 0, Ah2, uacc, nh, g, c);
      stage16(W2_l, 1024, fc * 256, WB2, tid);
      bar_v2();
      // sU1: U-gemm h1 (B1) + relu epi -> Rq | issue W2cfc-h1 -> B3
      gemm_half(WB1, 1, Ah2, uacc, nh, g, c);
      epi_rm<true>(uacc, pb1 + l * 512 + fc * 128, Rq, nh, g, c);
      stage16(W2_l, 1024, fc * 256 + 128, WB3, tid);
      bar_v2();
      // sY0: loadA(U); Y-gemm h0 (B2) into x | issue W1c(fc+1)-h0 -> B0 (fc<3)
      loadA_rm(Rq, g, c, Au);
      gemm_half(WB2, 0, Au, x, nh, g, c);
      if (fc < 3) { stage16(W1_l + (fc + 1) * 32768, 256, 0, WB0, tid); bar_v2(); }
      else bar_v0();
      // sY1: Y-gemm h1 (B3) into x | issue W1c(fc+1)-h1 -> B1 (fc<3)
      gemm_half(WB3, 1, Au, x, nh, g, c);
      if (fc < 3) { stage16(W1_l + (fc + 1) * 32768, 256, 128, WB1, tid); bar_v2(); }
      else {
#pragma unroll
        for (int nt = 0; nt < 4; ++nt) {
          float bb = pb2[l * 128 + nh * 64 + nt * 16 + c];
#pragma unroll
          for (int mt = 0; mt < 2; ++mt)
#pragma unroll
            for (int r = 0; r < 4; ++r) x[mt][nt][r] += bb;
        }
        bar_lg();
      }
    }
  }

  // ---------------- output: LDS bounce -> fully coalesced fp32 stores ----------------
#pragma unroll
  for (int nt = 0; nt < 4; ++nt) {
    int col = nh * 64 + nt * 16 + c;
#pragma unroll
    for (int mt = 0; mt < 2; ++mt)
      *(f32x4*)(pairb + mt * 8192 + col * 64 + g * 16) = x[mt][nt];
  }
  bar_lg();
  {
    const int smp = S0 + 2 * p + nh;
    const u8* src = pairb + nh * 8192;
#pragma unroll
    for (int it = 0; it < 8; ++it) {
      int n = it * 2 + (lane >> 5);
      int slot = lane & 31;
      f32x4 v;
#pragma unroll
      for (int e = 0; e < 4; ++e)
        v[e] = *(const float*)(src + (u32)((slot * 4 + e) * 64 + n * 4));
      *(f32x4*)(out + (size_t)smp * 2048 + n * 128 + slot * 4) = v;
    }
  }
}

// ---------------- prep kernels ----------------
__global__ void prep_feats_k(const float* __restrict__ pos, const float* __restrict__ vel,
                             bf16* __restrict__ feats) {
  int i = blockIdx.x * 256 + threadIdx.x;
  if (i >= B_TOT * 64) return;
  int b = i >> 6, k = i & 63;
  float v = (k < 32) ? pos[b * 32 + k] : vel[b * 32 + (k - 32)];
  feats[i] = (bf16)v;
}

// dst[m][cc][rr] = (bf16) src[m][rr][cc]; src is [mats][R][C] fp32
__global__ void prep_tr_k(const float* __restrict__ src, bf16* __restrict__ dst,
                          int R, int C, int total) {
  int i = blockIdx.x * 256 + threadIdx.x;
  if (i >= total) return;
  int rc = R * C;
  int m = i / rc, rem = i % rc;
  int cc = rem / R, rr = rem % R;
  dst[i] = (bf16)src[(size_t)m * rc + rr * C + cc];
}

extern "C" void kernel_launch(void* const* d_in, const int* in_sizes, int n_in,
                              void* d_out, int out_size, void* d_ws, size_t ws_size,
                              hipStream_t stream) {
  const float* jp  = (const float*)d_in[0];
  const float* jv  = (const float*)d_in[1];
  const int*   adj = (const int*)d_in[2];
  const float* eW  = (const float*)d_in[3];
  const float* eB  = (const float*)d_in[4];
  const float* pE  = (const float*)d_in[5];
  const float* Wq  = (const float*)d_in[6];  const float* bq = (const float*)d_in[7];
  const float* Wk  = (const float*)d_in[8];  const float* bk = (const float*)d_in[9];
  const float* Wv  = (const float*)d_in[10]; const float* bv = (const float*)d_in[11];
  const float* Wo  = (const float*)d_in[12]; const float* bo = (const float*)d_in[13];
  const float* g1  = (const float*)d_in[14]; const float* be1 = (const float*)d_in[15];
  const float* g2  = (const float*)d_in[16]; const float* be2 = (const float*)d_in[17];
  const float* W1  = (const float*)d_in[18]; const float* b1 = (const float*)d_in[19];
  const float* W2  = (const float*)d_in[20]; const float* b2 = (const float*)d_in[21];

  bf16* ws    = (bf16*)d_ws;
  bf16* feats = ws;                    // 1048576
  bf16* embWT = ws + 1048576;          // 131072  [16*128 outcol][64 in]
  bf16* wqT   = embWT + 131072;        // 65536   [4][128 out][128 in]
  bf16* wkT   = wqT + 65536;
  bf16* wvT   = wkT + 65536;
  bf16* woT   = wvT + 65536;
  bf16* w1T   = woT + 65536;           // 262144  [4][512 f][128 in]
  bf16* w2T   = w1T + 262144;          // 262144  [4][128 out][512 f]

  prep_feats_k<<<(B_TOT * 64 + 255) / 256, 256, 0, stream>>>(jp, jv, feats);
  prep_tr_k<<<512, 256, 0, stream>>>(eW, embWT, 64, 128, 131072);
  prep_tr_k<<<256, 256, 0, stream>>>(Wq, wqT, 128, 128, 65536);
  prep_tr_k<<<256, 256, 0, stream>>>(Wk, wkT, 128, 128, 65536);
  prep_tr_k<<<256, 256, 0, stream>>>(Wv, wvT, 128, 128, 65536);
  prep_tr_k<<<256, 256, 0, stream>>>(Wo, woT, 128, 128, 65536);
  prep_tr_k<<<1024, 256, 0, stream>>>(W1, w1T, 128, 512, 262144);
  prep_tr_k<<<1024, 256, 0, stream>>>(W2, w2T, 512, 128, 262144);

  bot_main<<<NWGS, 512, 0, stream>>>(adj, eB, pE, bq, bk, bv, bo,
                                     g1, be1, g2, be2, b1, b2,
                                     feats, embWT, wqT, wkT, wvT, woT, w1T, w2T,
                                     (float*)d_out);
}